// Round 3
// baseline (806.170 us; speedup 1.0000x reference)
//
#include <hip/hip_runtime.h>
#include <hip/hip_bf16.h>
#include <math.h>

// Problem constants
#define B_  2
#define T_  2048
#define C_  1536
#define H_  12
#define KV_ 4
#define D_  128
#define M_  (B_*T_)   // 4096 rows
#define REP_ (H_/KV_) // 3
#define NQKV_ 2560    // fused q|k|v output width
#define KK_  1536     // K for both big GEMMs
#define NKT_ 24       // KK_/64 K-tiles

typedef __bf16 bf16x8 __attribute__((ext_vector_type(8)));
typedef float  f32x4  __attribute__((ext_vector_type(4)));
typedef unsigned u32x4 __attribute__((ext_vector_type(4)));

union BCast { u32x4 u; bf16x8 b; };

__device__ inline bf16x8 ldb8(const ushort* p) {
    BCast c; c.u = *reinterpret_cast<const u32x4*>(p); return c.b;
}

__device__ inline ushort f2bf(float f) {
    union { float f; unsigned u; } v; v.f = f;
    unsigned u = v.u;
    return (ushort)((u + 0x7FFF + ((u >> 16) & 1)) >> 16);
}

__device__ inline float bf2f(ushort u) {
    union { unsigned u; float f; } v; v.u = (unsigned)u << 16;
    return v.f;
}

// async global->LDS, 16 bytes per lane; lds base must be wave-uniform
__device__ inline void async_copy16(const ushort* g, ushort* l) {
    __builtin_amdgcn_global_load_lds(
        (const __attribute__((address_space(1))) unsigned*)g,
        (__attribute__((address_space(3))) unsigned*)l, 16, 0, 0);
}

// d-permutation for rope-pair locality: swap middle two 32-blocks of each head.
__device__ __host__ inline int dperm(int d) {
    return (d < 32) ? d : (d < 64 ? d + 32 : (d < 96 ? d - 32 : d));
}

// counted waits: reads complete in-order on the DS queue, so lgkmcnt(N)
// certifies exactly the oldest (outstanding-N) reads. sched_barrier pins
// issue order around the wait (rule 18).
#define WAIT_LGKM(n) { __builtin_amdgcn_sched_barrier(0);                  \
    __builtin_amdgcn_s_waitcnt(0xC07F | ((n) << 8));                       \
    __builtin_amdgcn_sched_barrier(0); }
#define WAIT_VM(code) { __builtin_amdgcn_sched_barrier(0);                 \
    __builtin_amdgcn_s_waitcnt(code);                                      \
    __builtin_amdgcn_sched_barrier(0); }

#define MFMA16(va, vb, d) d = __builtin_amdgcn_mfma_f32_16x16x32_bf16(va, vb, d, 0, 0, 0)

#define CLUSTER(AARR, BARR, MB, NB)                                        \
    __builtin_amdgcn_s_setprio(1);                                         \
    _Pragma("unroll")                                                      \
    for (int mf = 0; mf < 4; mf++)                                         \
        _Pragma("unroll")                                                  \
        for (int nf = 0; nf < 2; nf++) {                                   \
            MFMA16(AARR[mf*2+0], BARR[nf*2+0], acc[(MB)+mf][(NB)+nf]);     \
            MFMA16(AARR[mf*2+1], BARR[nf*2+1], acc[(MB)+mf][(NB)+nf]);     \
        }                                                                  \
    __builtin_amdgcn_s_setprio(0);

// ds_read bursts from precomputed per-lane swizzled base pointers (imm offsets)
#define RD_AL(bo_) { _Pragma("unroll") for (int mf = 0; mf < 4; mf++) {    \
        aL[mf*2+0] = ldb8(aB0 + (bo_) + mf*1024);                          \
        aL[mf*2+1] = ldb8(aB1 + (bo_) + mf*1024); } }
#define RD_AH(bo_) { _Pragma("unroll") for (int mf = 0; mf < 4; mf++) {    \
        aH[mf*2+0] = ldb8(aB0 + (bo_) + 4096 + mf*1024);                   \
        aH[mf*2+1] = ldb8(aB1 + (bo_) + 4096 + mf*1024); } }
#define RD_B0(bo_) { _Pragma("unroll") for (int nf = 0; nf < 2; nf++) {    \
        b0[nf*2+0] = ldb8(bB0 + (bo_) + nf*1024);                          \
        b0[nf*2+1] = ldb8(bB1 + (bo_) + nf*1024); } }
#define RD_B1(bo_) { _Pragma("unroll") for (int nf = 0; nf < 2; nf++) {    \
        b1[nf*2+0] = ldb8(bB0 + (bo_) + 2048 + nf*1024);                   \
        b1[nf*2+1] = ldb8(bB1 + (bo_) + 2048 + nf*1024); } }

// ---------------------------------------------------------------------------
// 256x256 GEMM, counted-lgkm pipelined schedule: C[M,N] = A[M,K]*B[N,K]^T
// 512 thr / 8 waves (2M x 4N); wave tile 128x64 = acc[8][4] f32x4. BK=64.
// LDS [op][buf][half][128x64 bf16] = 128 KiB, XOR-swizzled (both-sides, r21).
// Steady state entering kt (in flight, oldest first): aL(8), b0(4), b1(4).
//   issue aH(8) -> lgkm(12) [aL,b0 ready] -> Q1(aL*b0)
//   -> lgkm(8) [b1 ready] -> Q2(aL*b1)
//   -> lgkm(0) [aH ready; ALL cur-buf reads done]
//   -> Bar1 -> stage kt+2 into cur -> vmcnt(8) [kt+1 landed] -> Bar2
//   -> issue aL'(8)@nxt -> Q3(aH*b1) -> Q4(aH*b0) -> issue b0',b1'(8)@nxt.
// Every wait targets reads issued >=1 MFMA-cluster earlier, so only LDS
// *throughput* sits on the critical path, overlapped with the matrix pipe.
// Register ring is WAR-clean: each frag array's refill issues after its last
// consumer in program order (anti-deps enforce it).
// EPI 0 = qkv (rope/rms q,k | v->vbuf), EPI 1 = fp32 C.
// ---------------------------------------------------------------------------
template<int EPI>
__global__ __launch_bounds__(512) void gemm256(const ushort* __restrict__ A,
                                               const ushort* __restrict__ Bm,
                                               ushort* __restrict__ Qp,
                                               ushort* __restrict__ Kp,
                                               ushort* __restrict__ vbuf,
                                               float* __restrict__ Cf,
                                               const float* __restrict__ cosb,
                                               const float* __restrict__ sinb) {
    __shared__ ushort lds[2][2][2][8192];   // [op A=0/B=1][buf][half][128*64]
    const int tid  = threadIdx.x;
    const int wave = tid >> 6, lane = tid & 63;
    const int m16 = lane & 15, quad = lane >> 4;
    const int WM = wave >> 2, WN = wave & 3;
    const int brow = (WN & 1) << 6;

    // XCD-aware bijective remap, M-fastest within each XCD chunk.
    const int nwg  = gridDim.x * gridDim.y;
    const int orig = blockIdx.y * gridDim.x + blockIdx.x;
    const int vid  = (orig & 7) * (nwg >> 3) + (orig >> 3);
    const int bxT  = vid >> 4;              // gridY = M_/256 = 16
    const int byT  = vid & 15;
    const int bm = byT << 8, bn = bxT << 8;

    // staging: linear LDS dest, inverse-swizzled global source (rule 21)
    const int r = tid >> 3;                              // 0..63
    const int slot8 = ((tid & 7) ^ (r & 7)) << 3;        // swizzled col (elems)
    const ushort* Ag = A  + (size_t)(bm + r) * KK_ + slot8;
    const ushort* Bg = Bm + (size_t)(bn + r) * KK_ + slot8;
    const size_t row64 = (size_t)64 * KK_;
    const size_t hskip = (size_t)128 * KK_;

    auto stage2 = [&](const ushort* Gp, int buf, int op, int kc) {
        ushort* base = &lds[0][0][0][0] + op * 32768 + buf * 16384 + wave * 512;
        const ushort* g = Gp + kc;
        async_copy16(g,                 base);           // half0 rows w*8
        async_copy16(g + row64,         base + 4096);    // half0 rows 64+w*8
        async_copy16(g + hskip,         base + 8192);    // half1 rows w*8
        async_copy16(g + hskip + row64, base + 8192 + 4096);
    };

    // per-lane swizzled frag base pointers (ushort units; row=64u, half=8192u,
    // buf=16384u, opB=32768u). byte swizzle: col-bits4..6 ^= row&7.
    const int swzu = (m16 & 7) << 3;
    const int k0u  = (quad * 8) ^ swzu;
    const int k1u  = (32 + quad * 8) ^ swzu;
    const ushort* ldsu = &lds[0][0][0][0];
    const ushort* aB0 = ldsu + (WM ? 8192 : 0) + (m16 << 6) + k0u;
    const ushort* aB1 = ldsu + (WM ? 8192 : 0) + (m16 << 6) + k1u;
    const ushort* bB0 = ldsu + 32768 + ((WN >> 1) ? 8192 : 0) + ((brow + m16) << 6) + k0u;
    const ushort* bB1 = ldsu + 32768 + ((WN >> 1) ? 8192 : 0) + ((brow + m16) << 6) + k1u;

    f32x4 acc[8][4];
    #pragma unroll
    for (int i = 0; i < 8; i++)
        #pragma unroll
        for (int j = 0; j < 4; j++) acc[i][j] = (f32x4){0.f, 0.f, 0.f, 0.f};

    bf16x8 aL[8], aH[8], b0[4], b1[4];

    // prologue: stage K-tiles 0,1; wait tile0; prime the read ring @buf0
    stage2(Bg, 0, 1, 0);  stage2(Ag, 0, 0, 0);
    stage2(Bg, 1, 1, 64); stage2(Ag, 1, 0, 64);
    WAIT_VM(0x0F78);                       // vmcnt(8): tile0 landed
    __builtin_amdgcn_s_barrier();
    __builtin_amdgcn_sched_barrier(0);
    RD_AL(0); RD_B0(0); RD_B1(0);          // 16 in flight

    #pragma unroll 1
    for (int kt = 0; kt < NKT_; kt++) {
        const int bo  = (kt & 1) ? 16384 : 0;
        const int boN = 16384 - bo;
        const bool stg  = (kt < NKT_ - 2);
        const bool last = (kt == NKT_ - 1);
        const int kc2 = (kt + 2) << 6;

        RD_AH(bo);                         // (a): 8 reads, fly under Q1+Q2
        WAIT_LGKM(12);                     // (b): aL,b0 ready
        CLUSTER(aL, b0, 0, 0);             // Q1
        WAIT_LGKM(8);                      // (d): b1 ready
        CLUSTER(aL, b1, 0, 2);             // Q2
        WAIT_LGKM(0);                      // (f): aH ready; all cur reads done
        if (!last) {
            __builtin_amdgcn_s_barrier();  // Bar1: cur buf globally read-done
            __builtin_amdgcn_sched_barrier(0);
            if (stg) {
                stage2(Bg, kt & 1, 1, kc2);
                stage2(Ag, kt & 1, 0, kc2);
                WAIT_VM(0x0F78);           // vmcnt(8): kt+1 landed
            } else {
                WAIT_VM(0x0F70);           // vmcnt(0): drain tail
            }
            __builtin_amdgcn_s_barrier();  // Bar2: nxt buf certified
            __builtin_amdgcn_sched_barrier(0);
            RD_AL(boN);                    // (h): next aL under Q3/Q4
            CLUSTER(aH, b1, 4, 2);         // Q3 (last use of b1)
            CLUSTER(aH, b0, 4, 0);         // Q4 (last use of b0)
            RD_B0(boN); RD_B1(boN);        // (k): next b0,b1
        } else {
            CLUSTER(aH, b1, 4, 2);
            CLUSTER(aH, b0, 4, 0);
        }
    }
    __syncthreads();   // quiesce before epilogue LDS reuse

    // ---------------- epilogues ----------------
    if constexpr (EPI == 0) {
        if (bn >= 2048) {
            // v tile: plain bf16 to vbuf [row][512] (original d-order)
            const int cb = bn - 2048 + WN*64;
            #pragma unroll
            for (int m = 0; m < 8; m++) {
                const int rl = WM*128 + (m>>2)*64 + (m&3)*16 + quad*4;
                #pragma unroll
                for (int reg = 0; reg < 4; reg++) {
                    ushort* vr = vbuf + (size_t)(bm + rl + reg) * 512 + cb + m16;
                    #pragma unroll
                    for (int j = 0; j < 4; j++)
                        vr[(j>>1)*32 + (j&1)*16] = f2bf(acc[m][j][reg]);
                }
            }
        } else {
            // q/k tile: RMS (rotation-invariant, from raw acc) + rope
            float* ssqS = (float*)&lds[0][0][0][0];   // 4KB scratch
            #pragma unroll
            for (int m = 0; m < 8; m++) {
                #pragma unroll
                for (int reg = 0; reg < 4; reg++) {
                    float v = acc[m][0][reg]*acc[m][0][reg] + acc[m][1][reg]*acc[m][1][reg]
                            + acc[m][2][reg]*acc[m][2][reg] + acc[m][3][reg]*acc[m][3][reg];
                    v += __shfl_xor(v, 1); v += __shfl_xor(v, 2);
                    v += __shfl_xor(v, 4); v += __shfl_xor(v, 8);
                    if (m16 == 0) {
                        const int rl = WM*128 + (m>>2)*64 + (m&3)*16 + quad*4 + reg;
                        ssqS[rl*4 + WN] = v;   // wave's 64-col partial
                    }
                }
            }
            __syncthreads();

            const bool isq = (bn < 1536);
            const float osc = isq ? (1.2f * 1.2f * 0.08838834764831845f) : 1.0f;
            const int hh = (isq ? (bn >> 7) : ((bn - 1536) >> 7)) + (WN >> 1);
            const int nh  = isq ? H_ : KV_;
            ushort* outp  = isq ? Qp : Kp;

            #pragma unroll
            for (int m = 0; m < 8; m++) {
                #pragma unroll
                for (int reg = 0; reg < 4; reg++) {
                    const int rl = WM*128 + (m>>2)*64 + (m&3)*16 + quad*4 + reg;
                    const int row = bm + rl;
                    const float tot = ssqS[rl*4 + (WN & ~1)] + ssqS[rl*4 + (WN | 1)];
                    const float sc = rsqrtf(tot * (1.0f/128.0f) + 1.1920928955078125e-07f) * osc;
                    const int b = row >> 11, t = row & (T_ - 1);
                    ushort* orow = outp + ((size_t)(b * nh + hh) * T_ + t) * D_;
                    #pragma unroll
                    for (int nf = 0; nf < 2; nf++) {
                        const int ipair = (WN & 1) * 32 + nf*16 + m16;
                        const float c = cosb[t*64 + ipair], s = sinb[t*64 + ipair];
                        const float x1 = acc[m][nf][reg], x2 = acc[m][2+nf][reg];
                        const int oc = (WN & 1) * 64 + nf*16 + m16;
                        orow[oc]      = f2bf((x1*c + x2*s) * sc);
                        orow[oc + 32] = f2bf((x2*c - x1*s) * sc);
                    }
                }
            }
        }
    } else {
        // plain fp32 C
        #pragma unroll
        for (int m = 0; m < 8; m++) {
            const int rl = WM*128 + (m>>2)*64 + (m&3)*16 + quad*4;
            #pragma unroll
            for (int reg = 0; reg < 4; reg++) {
                float* cr = Cf + (size_t)(bm + rl + reg) * C_ + bn + WN*64 + m16;
                #pragma unroll
                for (int j = 0; j < 4; j++)
                    cr[(j>>1)*32 + (j&1)*16] = acc[m][j][reg];
            }
        }
    }
}

// ---------------------------------------------------------------------------
// Fused segmented fp32->bf16 cast of x, Wq, Wk, Wv, Wproj (one launch).
// ---------------------------------------------------------------------------
#define SEG0 1572864   // x      : 4096*1536/4
#define SEG1 2162688   // + Wq   : 1536*1536/4
#define SEG2 2359296   // + Wk   : 512*1536/4
#define SEG3 2555904   // + Wv   : 512*1536/4
#define SEG4 3145728   // + Wproj: 1536*1536/4
#define ROW4 384       // float4s per 1536-col row
__global__ __launch_bounds__(256) void cast_all(const float* __restrict__ x,
                                                const float* __restrict__ Wq,
                                                const float* __restrict__ Wk,
                                                const float* __restrict__ Wv,
                                                const float* __restrict__ Wp,
                                                ushort* __restrict__ xb,
                                                ushort* __restrict__ Wqkvb,
                                                ushort* __restrict__ Wpb) {
    const int i = blockIdx.x * 256 + threadIdx.x;
    float4 v; size_t dst4; ushort* dstp;
    if (i < SEG0) {
        v = ((const float4*)x)[i]; dstp = xb; dst4 = i;
    } else if (i < SEG1) {
        const int j = i - SEG0;
        const int r = j / ROW4, c4 = j - r * ROW4;
        const int d = r & 127, hh = r >> 7;
        v = ((const float4*)Wq)[j]; dstp = Wqkvb;
        dst4 = (size_t)(hh * 128 + dperm(d)) * ROW4 + c4;
    } else if (i < SEG2) {
        const int j = i - SEG1;
        const int r = j / ROW4, c4 = j - r * ROW4;
        const int d = r & 127, g = r >> 7;
        v = ((const float4*)Wk)[j]; dstp = Wqkvb;
        dst4 = (size_t)(1536 + g * 128 + dperm(d)) * ROW4 + c4;
    } else if (i < SEG3) {
        const int j = i - SEG2;
        v = ((const float4*)Wv)[j]; dstp = Wqkvb;
        dst4 = (size_t)2048 * ROW4 + j;
    } else {
        const int j = i - SEG3;
        v = ((const float4*)Wp)[j]; dstp = Wpb; dst4 = j;
    }
    ((ushort4*)dstp)[dst4] = make_ushort4(f2bf(v.x), f2bf(v.y), f2bf(v.z), f2bf(v.w));
}

// ---------------------------------------------------------------------------
// Fused ve-gate + transpose: Vt[b][g][d][s] = vbuf[bt][g*128+d] + gate*ve
// ---------------------------------------------------------------------------
__global__ __launch_bounds__(256) void gate_vt(const ushort* __restrict__ vbuf,
                                               const float* __restrict__ x,
                                               const float* __restrict__ ve,
                                               const float* __restrict__ Wg,
                                               ushort* __restrict__ Vt) {
    const int t0 = blockIdx.x * 64, g = blockIdx.y, b = blockIdx.z;
    __shared__ float gateS[64];
    __shared__ ushort tile[128][66];   // [d][t], padded
    const int tid = threadIdx.x;
    if (tid < 64) {
        const float* xr = x + (size_t)(b * T_ + t0 + tid) * C_;
        float acc = 0.f;
        #pragma unroll
        for (int c = 0; c < 12; c++) acc += xr[c] * Wg[g * 12 + c];
        gateS[tid] = 3.0f / (1.0f + __expf(-acc));
    }
    __syncthreads();
    #pragma unroll
    for (int i = 0; i < 32; i++) {
        int idx = i * 256 + tid;       // 0..8191
        int r = idx >> 7;              // t within tile
        int d = idx & 127;
        size_t offv = (size_t)(b * T_ + t0 + r) * 512 + g * D_ + d;
        tile[d][r] = f2bf(bf2f(vbuf[offv]) + gateS[r] * ve[offv]);
    }
    __syncthreads();
    ushort* ob = Vt + ((size_t)(b * KV_ + g) * D_) * T_ + t0;
    #pragma unroll
    for (int i = 0; i < 32; i++) {
        int idx = i * 256 + tid;
        int d = idx >> 6;              // 0..127
        int c = idx & 63;
        ob[(size_t)d * T_ + c] = tile[d][c];
    }
}

// ---------------------------------------------------------------------------
// Flash attention: block = (b, h, 64 queries), 4 waves x 16 queries.
// ---------------------------------------------------------------------------
__global__ __launch_bounds__(256, 3) void attn_mfma(const ushort* __restrict__ Qp,
                                                    const ushort* __restrict__ Kp,
                                                    const ushort* __restrict__ Vt,
                                                    ushort* __restrict__ Y,
                                                    const int* __restrict__ wptr) {
    const int t0 = blockIdx.x * 64;
    const int h  = blockIdx.y, b = blockIdx.z;
    const int g  = h / REP_;
    const int tid  = threadIdx.x;
    const int wave = tid >> 6, lane = tid & 63;
    const int m16 = lane & 15, quad = lane >> 4;

    __shared__ ushort Ks[4 * 32 * 32];   // 8 KB
    __shared__ ushort Vs[128 * 32];      // 8 KB
    __shared__ ushort Pl[4][16 * 40];    // 5 KB, per-wave P buffers

    const int w = *wptr;
    const bool windowed = (w >= 0 && w < T_);
    const unsigned wu = windowed ? (unsigned)w : 0x7FFFFFFFu;
    int s_lo = 0;
    if (windowed) { s_lo = t0 - w; if (s_lo < 0) s_lo = 0; }
    const int s_hi = t0 + 63;
    const int ss0 = s_lo & ~31;
    const int tw = t0 + wave * 16;

    const ushort* qrow = Qp + ((size_t)(b * H_ + h) * T_ + tw + m16) * D_ + quad * 8;
    bf16x8 qa[4];
    #pragma unroll
    for (int kc = 0; kc < 4; kc++) qa[kc] = ldb8(qrow + kc * 32);

    const ushort* kbase = Kp + (size_t)(b * KV_ + g) * T_ * D_;
    const ushort* vbase = Vt + (size_t)(b * KV_ + g) * D_ * T_;

    const int c0 = wave, c1 = wave + 4;
    const ushort* kg0 = kbase + (size_t)((c0 & 1) * 16 + (lane >> 2)) * D_ + (c0 >> 1) * 32 + (lane & 3) * 8;
    const ushort* kg1 = kbase + (size_t)((c1 & 1) * 16 + (lane >> 2)) * D_ + (c1 >> 1) * 32 + (lane & 3) * 8;
    ushort* kl0 = Ks + c0 * 512;
    ushort* kl1 = Ks + c1 * 512;
    const ushort* vg0 = vbase + (size_t)(c0 * 16 + (lane >> 2)) * T_ + (lane & 3) * 8;
    const ushort* vg1 = vbase + (size_t)(c1 * 16 + (lane >> 2)) * T_ + (lane & 3) * 8;
    ushort* vl0 = Vs + c0 * 512;
    ushort* vl1 = Vs + c1 * 512;

    f32x4 o[8];
    #pragma unroll
    for (int dt = 0; dt < 8; dt++) o[dt] = (f32x4){0.f, 0.f, 0.f, 0.f};
    f32x4 lacc = (f32x4){0.f, 0.f, 0.f, 0.f};
    BCast onesc; onesc.u = (u32x4){0x3F803F80u, 0x3F803F80u, 0x3F803F80u, 0x3F803F80u};
    const bf16x8 ones = onesc.b;
    ushort* pw = &Pl[wave][0];

    for (int ss = ss0; ss <= s_hi; ss += 32) {
        const size_t koff = (size_t)ss * D_;
        async_copy16(kg0 + koff, kl0);
        async_copy16(kg1 + koff, kl1);
        async_copy16(vg0 + ss,   vl0);
        async_copy16(vg1 + ss,   vl1);
        __syncthreads();

        f32x4 s0 = (f32x4){0.f,0.f,0.f,0.f};
        f32x4 s1 = (f32x4){0.f,0.f,0.f,0.f};
        #pragma unroll
        for (int kc = 0; kc < 4; kc++) {
            bf16x8 kf0 = ldb8(Ks + kc * 1024 + m16 * 32 + quad * 8);
            bf16x8 kf1 = ldb8(Ks + kc * 1024 + (16 + m16) * 32 + quad * 8);
            s0 = __builtin_amdgcn_mfma_f32_16x16x32_bf16(qa[kc], kf0, s0, 0, 0, 0);
            s1 = __builtin_amdgcn_mfma_f32_16x16x32_bf16(qa[kc], kf1, s1, 0, 0, 0);
        }

        const int sA = ss + m16, sB = ss + 16 + m16;
        #pragma unroll
        for (int reg = 0; reg < 4; reg++) {
            const int t = tw + quad * 4 + reg;
            const float pa = ((unsigned)(t - sA) <= wu) ? __expf(s0[reg]) : 0.f;
            const float pb = ((unsigned)(t - sB) <= wu) ? __expf(s1[reg]) : 0.f;
            pw[(quad * 4 + reg) * 40 + m16]      = f2bf(pa);
            pw[(quad * 4 + reg) * 40 + 16 + m16] = f2bf(pb);
        }

        __builtin_amdgcn_s_waitcnt(0xc07f);   // lgkmcnt(0), leave vmcnt alone
        bf16x8 pfrag = ldb8(pw + m16 * 40 + quad * 8);

        #pragma unroll
        for (int dt = 0; dt < 8; dt++) {
            bf16x8 vf = ldb8(Vs + (dt * 16 + m16) * 32 + quad * 8);
            o[dt] = __builtin_amdgcn_mfma_f32_16x16x32_bf16(pfrag, vf, o[dt], 0, 0, 0);
        }
        lacc = __builtin_amdgcn_mfma_f32_16x16x32_bf16(pfrag, ones, lacc, 0, 0, 0);
        __syncthreads();
    }

    float inv[4];
    #pragma unroll
    for (int reg = 0; reg < 4; reg++) inv[reg] = 1.0f / lacc[reg];
    ushort* yb = Y + ((size_t)(b * T_ + tw + quad * 4) * H_ + h) * D_ + m16;
    #pragma unroll
    for (int reg = 0; reg < 4; reg++)
        #pragma unroll
        for (int dt = 0; dt < 8; dt++)
            yb[(size_t)reg * H_ * D_ + dt * 16] = f2bf(o[dt][reg] * inv[reg]);
}

// ---------------------------------------------------------------------------
extern "C" void kernel_launch(void* const* d_in, const int* in_sizes, int n_in,
                              void* d_out, int out_size, void* d_ws, size_t ws_size,
                              hipStream_t stream) {
    const float* x     = (const float*)d_in[0];
    const float* ve    = (const float*)d_in[1];
    const float* cosb  = (const float*)d_in[2];
    const float* sinb  = (const float*)d_in[3];
    const float* Wq    = (const float*)d_in[4];
    const float* Wk    = (const float*)d_in[5];
    const float* Wv    = (const float*)d_in[6];
    const float* Wproj = (const float*)d_in[7];
    const float* Wg    = (const float*)d_in[8];
    const int*   wptr  = (const int*)d_in[9];
    float* out = (float*)d_out;

    // workspace layout (all bf16/ushort), ~63 MB
    ushort* xb    = (ushort*)d_ws;                    // M*C
    ushort* vbuf  = xb    + (size_t)M_ * C_;          // M*512
    ushort* Qp    = vbuf  + (size_t)M_ * 512;         // M*C (permuted d)
    ushort* Kp    = Qp    + (size_t)M_ * C_;          // M*512 (permuted d)
    ushort* Vt    = Kp    + (size_t)M_ * 512;         // M*512
    ushort* yb16  = Vt    + (size_t)M_ * 512;         // M*C
    ushort* Wqkvb = yb16  + (size_t)M_ * C_;          // 2560*C (q/k rows dperm'd)
    ushort* Wpb   = Wqkvb + (size_t)NQKV_ * C_;       // C*C

    cast_all<<<SEG4 / 256, 256, 0, stream>>>(x, Wq, Wk, Wv, Wproj, xb, Wqkvb, Wpb);

    gemm256<0><<<dim3(NQKV_ / 256, M_ / 256), 512, 0, stream>>>(
        xb, Wqkvb, Qp, Kp, vbuf, nullptr, cosb, sinb);

    gate_vt<<<dim3(T_ / 64, KV_, B_), 256, 0, stream>>>(vbuf, x, ve, Wg, Vt);

    attn_mfma<<<dim3(T_ / 64, H_, B_), 256, 0, stream>>>(Qp, Kp, Vt, yb16, wptr);

    gemm256<1><<<dim3(C_ / 256, M_ / 256), 512, 0, stream>>>(
        yb16, Wpb, nullptr, nullptr, nullptr, out, nullptr, nullptr);
}

// Round 4
// 269.275 us; speedup vs baseline: 2.9939x; 2.9939x over previous
//
#include <hip/hip_runtime.h>
#include <hip/hip_bf16.h>
#include <math.h>

// Problem constants
#define B_  2
#define T_  2048
#define C_  1536
#define H_  12
#define KV_ 4
#define D_  128
#define M_  (B_*T_)   // 4096 rows
#define REP_ (H_/KV_) // 3
#define NQKV_ 2560    // fused q|k|v output width
#define KK_  1536     // K for both big GEMMs
#define NKT_ 24       // KK_/64 K-tiles

typedef __bf16 bf16x8 __attribute__((ext_vector_type(8)));
typedef float  f32x4  __attribute__((ext_vector_type(4)));
typedef unsigned u32x4 __attribute__((ext_vector_type(4)));

union BCast { u32x4 u; bf16x8 b; };

__device__ inline bf16x8 ldb8(const ushort* p) {
    BCast c; c.u = *reinterpret_cast<const u32x4*>(p); return c.b;
}

__device__ inline ushort f2bf(float f) {
    union { float f; unsigned u; } v; v.f = f;
    unsigned u = v.u;
    return (ushort)((u + 0x7FFF + ((u >> 16) & 1)) >> 16);
}

__device__ inline float bf2f(ushort u) {
    union { unsigned u; float f; } v; v.u = (unsigned)u << 16;
    return v.f;
}

// async global->LDS, 16 bytes per lane; lds base must be wave-uniform
__device__ inline void async_copy16(const ushort* g, ushort* l) {
    __builtin_amdgcn_global_load_lds(
        (const __attribute__((address_space(1))) unsigned*)g,
        (__attribute__((address_space(3))) unsigned*)l, 16, 0, 0);
}

// d-permutation for rope-pair locality: swap middle two 32-blocks of each head.
__device__ __host__ inline int dperm(int d) {
    return (d < 32) ? d : (d < 64 ? d + 32 : (d < 96 ? d - 32 : d));
}

#define MFMA16(va, vb, d) d = __builtin_amdgcn_mfma_f32_16x16x32_bf16(va, vb, d, 0, 0, 0)

// NOTE: no manual lgkm waits anywhere in the K-loop — the ds_reads are
// compiler-visible, and hipcc emits fine-grained counted lgkmcnt before the
// consuming MFMAs (m97 asm evidence). Manual drains (r1/r2) serialized the
// pipeline; manual counted ring (r3) spilled. Only vmcnt (for the
// compiler-invisible global_load_lds) and the two buffer-handoff barriers
// are hand-placed.
#define CLUSTER(AARR, BARR, MB, NB)                                        \
    __builtin_amdgcn_s_setprio(1);                                         \
    _Pragma("unroll")                                                      \
    for (int mf = 0; mf < 4; mf++)                                         \
        _Pragma("unroll")                                                  \
        for (int nf = 0; nf < 2; nf++) {                                   \
            MFMA16(AARR[mf*2+0], BARR[nf*2+0], acc[(MB)+mf][(NB)+nf]);     \
            MFMA16(AARR[mf*2+1], BARR[nf*2+1], acc[(MB)+mf][(NB)+nf]);     \
        }                                                                  \
    __builtin_amdgcn_s_setprio(0);

// ds_read bursts from precomputed per-lane swizzled base pointers (imm offsets)
#define RD_AL(bo_) { _Pragma("unroll") for (int mf = 0; mf < 4; mf++) {    \
        aL[mf*2+0] = ldb8(aB0 + (bo_) + mf*1024);                          \
        aL[mf*2+1] = ldb8(aB1 + (bo_) + mf*1024); } }
#define RD_AH(bo_) { _Pragma("unroll") for (int mf = 0; mf < 4; mf++) {    \
        aH[mf*2+0] = ldb8(aB0 + (bo_) + 4096 + mf*1024);                   \
        aH[mf*2+1] = ldb8(aB1 + (bo_) + 4096 + mf*1024); } }
#define RD_B0(bo_) { _Pragma("unroll") for (int nf = 0; nf < 2; nf++) {    \
        b0[nf*2+0] = ldb8(bB0 + (bo_) + nf*1024);                          \
        b0[nf*2+1] = ldb8(bB1 + (bo_) + nf*1024); } }
#define RD_B1(bo_) { _Pragma("unroll") for (int nf = 0; nf < 2; nf++) {    \
        b1[nf*2+0] = ldb8(bB0 + (bo_) + 2048 + nf*1024);                   \
        b1[nf*2+1] = ldb8(bB1 + (bo_) + 2048 + nf*1024); } }

// ---------------------------------------------------------------------------
// 256x256 GEMM, compiler-scheduled K-tile + raw-barrier double-buffer handoff.
// C[M,N] = A[M,K]*B[N,K]^T. 512 thr / 8 waves (2M x 4N); wave tile 128x64 =
// acc[8][4] f32x4. BK=64. LDS [op][buf][half][128x64 bf16] = 128 KiB,
// XOR-swizzled (both-sides, rule 21).
// Per K-tile: {24 ds_read + 4 MFMA clusters, compiler-interleaved; raw
// barriers between clusters align phases without draining}.
// Handoff: SB0; Bar1 (every wave's MFMAs consumed all cur-buf reads =>
// reads complete => staging into cur is safe); stage kt+2; vmcnt(8)
// (kt+1's 8 loads landed); Bar2; SB0 (next tile's reads can't hoist above).
// EPI 0 = qkv (rope/rms q,k | v->vbuf), EPI 1 = fp32 C.
// ---------------------------------------------------------------------------
template<int EPI>
__global__ __launch_bounds__(512) void gemm256(const ushort* __restrict__ A,
                                               const ushort* __restrict__ Bm,
                                               ushort* __restrict__ Qp,
                                               ushort* __restrict__ Kp,
                                               ushort* __restrict__ vbuf,
                                               float* __restrict__ Cf,
                                               const float* __restrict__ cosb,
                                               const float* __restrict__ sinb) {
    __shared__ ushort lds[2][2][2][8192];   // [op A=0/B=1][buf][half][128*64]
    const int tid  = threadIdx.x;
    const int wave = tid >> 6, lane = tid & 63;
    const int m16 = lane & 15, quad = lane >> 4;
    const int WM = wave >> 2, WN = wave & 3;
    const int brow = (WN & 1) << 6;

    // XCD-aware bijective remap, M-fastest within each XCD chunk.
    const int nwg  = gridDim.x * gridDim.y;
    const int orig = blockIdx.y * gridDim.x + blockIdx.x;
    const int vid  = (orig & 7) * (nwg >> 3) + (orig >> 3);
    const int bxT  = vid >> 4;              // gridY = M_/256 = 16
    const int byT  = vid & 15;
    const int bm = byT << 8, bn = bxT << 8;

    // staging: linear LDS dest, inverse-swizzled global source (rule 21)
    const int r = tid >> 3;                              // 0..63
    const int slot8 = ((tid & 7) ^ (r & 7)) << 3;        // swizzled col (elems)
    const ushort* Ag = A  + (size_t)(bm + r) * KK_ + slot8;
    const ushort* Bg = Bm + (size_t)(bn + r) * KK_ + slot8;
    const size_t row64 = (size_t)64 * KK_;
    const size_t hskip = (size_t)128 * KK_;

    auto stage2 = [&](const ushort* Gp, int buf, int op, int kc) {
        ushort* base = &lds[0][0][0][0] + op * 32768 + buf * 16384 + wave * 512;
        const ushort* g = Gp + kc;
        async_copy16(g,                 base);           // half0 rows w*8
        async_copy16(g + row64,         base + 4096);    // half0 rows 64+w*8
        async_copy16(g + hskip,         base + 8192);    // half1 rows w*8
        async_copy16(g + hskip + row64, base + 8192 + 4096);
    };

    // per-lane swizzled frag base pointers (ushort units; row=64u, half=8192u,
    // buf=16384u, opB=32768u). byte swizzle: col-bits4..6 ^= row&7.
    const int swzu = (m16 & 7) << 3;
    const int k0u  = (quad * 8) ^ swzu;
    const int k1u  = (32 + quad * 8) ^ swzu;
    const ushort* ldsu = &lds[0][0][0][0];
    const ushort* aB0 = ldsu + (WM ? 8192 : 0) + (m16 << 6) + k0u;
    const ushort* aB1 = ldsu + (WM ? 8192 : 0) + (m16 << 6) + k1u;
    const ushort* bB0 = ldsu + 32768 + ((WN >> 1) ? 8192 : 0) + ((brow + m16) << 6) + k0u;
    const ushort* bB1 = ldsu + 32768 + ((WN >> 1) ? 8192 : 0) + ((brow + m16) << 6) + k1u;

    f32x4 acc[8][4];
    #pragma unroll
    for (int i = 0; i < 8; i++)
        #pragma unroll
        for (int j = 0; j < 4; j++) acc[i][j] = (f32x4){0.f, 0.f, 0.f, 0.f};

    // prologue: stage K-tiles 0 (buf0) and 1 (buf1); certify tile0
    stage2(Bg, 0, 1, 0);  stage2(Ag, 0, 0, 0);
    stage2(Bg, 1, 1, 64); stage2(Ag, 1, 0, 64);
    __builtin_amdgcn_s_waitcnt(0x0F78);   // vmcnt(8): tile0 landed
    __builtin_amdgcn_sched_barrier(0);
    __builtin_amdgcn_s_barrier();
    __builtin_amdgcn_sched_barrier(0);

    #pragma unroll 1
    for (int kt = 0; kt < NKT_; kt++) {
        const int bo = (kt & 1) ? 16384 : 0;
        bf16x8 aL[8], aH[8], b0[4], b1[4];
        // 24 compiler-visible ds_reads; hipcc interleaves them with the
        // MFMA clusters below and emits counted lgkm waits itself.
        RD_AL(bo); RD_B0(bo); RD_B1(bo); RD_AH(bo);
        CLUSTER(aL, b0, 0, 0);
        __builtin_amdgcn_s_barrier();          // phase aligner (no drain)
        CLUSTER(aL, b1, 0, 2);
        __builtin_amdgcn_s_barrier();
        CLUSTER(aH, b1, 4, 2);
        __builtin_amdgcn_s_barrier();
        CLUSTER(aH, b0, 4, 0);
        if (kt < NKT_ - 1) {
            __builtin_amdgcn_sched_barrier(0);
            __builtin_amdgcn_s_barrier();      // Bar1: cur buf read-complete
            __builtin_amdgcn_sched_barrier(0);
            if (kt < NKT_ - 2) {
                stage2(Bg, kt & 1, 1, (kt + 2) << 6);
                stage2(Ag, kt & 1, 0, (kt + 2) << 6);
                __builtin_amdgcn_s_waitcnt(0x0F78);  // vmcnt(8): kt+1 landed
            } else {
                __builtin_amdgcn_s_waitcnt(0x0F70);  // vmcnt(0): drain tail
            }
            __builtin_amdgcn_sched_barrier(0);
            __builtin_amdgcn_s_barrier();      // Bar2: nxt buf certified
            __builtin_amdgcn_sched_barrier(0);
        }
    }
    __syncthreads();   // quiesce before epilogue LDS reuse

    // ---------------- epilogues ----------------
    if constexpr (EPI == 0) {
        if (bn >= 2048) {
            // v tile: plain bf16 to vbuf [row][512] (original d-order)
            const int cb = bn - 2048 + WN*64;
            #pragma unroll
            for (int m = 0; m < 8; m++) {
                const int rl = WM*128 + (m>>2)*64 + (m&3)*16 + quad*4;
                #pragma unroll
                for (int reg = 0; reg < 4; reg++) {
                    ushort* vr = vbuf + (size_t)(bm + rl + reg) * 512 + cb + m16;
                    #pragma unroll
                    for (int j = 0; j < 4; j++)
                        vr[(j>>1)*32 + (j&1)*16] = f2bf(acc[m][j][reg]);
                }
            }
        } else {
            // q/k tile: RMS (rotation-invariant, from raw acc) + rope
            float* ssqS = (float*)&lds[0][0][0][0];   // 4KB scratch
            #pragma unroll
            for (int m = 0; m < 8; m++) {
                #pragma unroll
                for (int reg = 0; reg < 4; reg++) {
                    float v = acc[m][0][reg]*acc[m][0][reg] + acc[m][1][reg]*acc[m][1][reg]
                            + acc[m][2][reg]*acc[m][2][reg] + acc[m][3][reg]*acc[m][3][reg];
                    v += __shfl_xor(v, 1); v += __shfl_xor(v, 2);
                    v += __shfl_xor(v, 4); v += __shfl_xor(v, 8);
                    if (m16 == 0) {
                        const int rl = WM*128 + (m>>2)*64 + (m&3)*16 + quad*4 + reg;
                        ssqS[rl*4 + WN] = v;   // wave's 64-col partial
                    }
                }
            }
            __syncthreads();

            const bool isq = (bn < 1536);
            const float osc = isq ? (1.2f * 1.2f * 0.08838834764831845f) : 1.0f;
            const int hh = (isq ? (bn >> 7) : ((bn - 1536) >> 7)) + (WN >> 1);
            const int nh  = isq ? H_ : KV_;
            ushort* outp  = isq ? Qp : Kp;

            #pragma unroll
            for (int m = 0; m < 8; m++) {
                #pragma unroll
                for (int reg = 0; reg < 4; reg++) {
                    const int rl = WM*128 + (m>>2)*64 + (m&3)*16 + quad*4 + reg;
                    const int row = bm + rl;
                    const float tot = ssqS[rl*4 + (WN & ~1)] + ssqS[rl*4 + (WN | 1)];
                    const float sc = rsqrtf(tot * (1.0f/128.0f) + 1.1920928955078125e-07f) * osc;
                    const int b = row >> 11, t = row & (T_ - 1);
                    ushort* orow = outp + ((size_t)(b * nh + hh) * T_ + t) * D_;
                    #pragma unroll
                    for (int nf = 0; nf < 2; nf++) {
                        const int ipair = (WN & 1) * 32 + nf*16 + m16;
                        const float c = cosb[t*64 + ipair], s = sinb[t*64 + ipair];
                        const float x1 = acc[m][nf][reg], x2 = acc[m][2+nf][reg];
                        const int oc = (WN & 1) * 64 + nf*16 + m16;
                        orow[oc]      = f2bf((x1*c + x2*s) * sc);
                        orow[oc + 32] = f2bf((x2*c - x1*s) * sc);
                    }
                }
            }
        }
    } else {
        // plain fp32 C
        #pragma unroll
        for (int m = 0; m < 8; m++) {
            const int rl = WM*128 + (m>>2)*64 + (m&3)*16 + quad*4;
            #pragma unroll
            for (int reg = 0; reg < 4; reg++) {
                float* cr = Cf + (size_t)(bm + rl + reg) * C_ + bn + WN*64 + m16;
                #pragma unroll
                for (int j = 0; j < 4; j++)
                    cr[(j>>1)*32 + (j&1)*16] = acc[m][j][reg];
            }
        }
    }
}

// ---------------------------------------------------------------------------
// Fused segmented fp32->bf16 cast of x, Wq, Wk, Wv, Wproj (one launch).
// ---------------------------------------------------------------------------
#define SEG0 1572864   // x      : 4096*1536/4
#define SEG1 2162688   // + Wq   : 1536*1536/4
#define SEG2 2359296   // + Wk   : 512*1536/4
#define SEG3 2555904   // + Wv   : 512*1536/4
#define SEG4 3145728   // + Wproj: 1536*1536/4
#define ROW4 384       // float4s per 1536-col row
__global__ __launch_bounds__(256) void cast_all(const float* __restrict__ x,
                                                const float* __restrict__ Wq,
                                                const float* __restrict__ Wk,
                                                const float* __restrict__ Wv,
                                                const float* __restrict__ Wp,
                                                ushort* __restrict__ xb,
                                                ushort* __restrict__ Wqkvb,
                                                ushort* __restrict__ Wpb) {
    const int i = blockIdx.x * 256 + threadIdx.x;
    float4 v; size_t dst4; ushort* dstp;
    if (i < SEG0) {
        v = ((const float4*)x)[i]; dstp = xb; dst4 = i;
    } else if (i < SEG1) {
        const int j = i - SEG0;
        const int r = j / ROW4, c4 = j - r * ROW4;
        const int d = r & 127, hh = r >> 7;
        v = ((const float4*)Wq)[j]; dstp = Wqkvb;
        dst4 = (size_t)(hh * 128 + dperm(d)) * ROW4 + c4;
    } else if (i < SEG2) {
        const int j = i - SEG1;
        const int r = j / ROW4, c4 = j - r * ROW4;
        const int d = r & 127, g = r >> 7;
        v = ((const float4*)Wk)[j]; dstp = Wqkvb;
        dst4 = (size_t)(1536 + g * 128 + dperm(d)) * ROW4 + c4;
    } else if (i < SEG3) {
        const int j = i - SEG2;
        v = ((const float4*)Wv)[j]; dstp = Wqkvb;
        dst4 = (size_t)2048 * ROW4 + j;
    } else {
        const int j = i - SEG3;
        v = ((const float4*)Wp)[j]; dstp = Wpb; dst4 = j;
    }
    ((ushort4*)dstp)[dst4] = make_ushort4(f2bf(v.x), f2bf(v.y), f2bf(v.z), f2bf(v.w));
}

// ---------------------------------------------------------------------------
// Fused ve-gate + transpose: Vt[b][g][d][s] = vbuf[bt][g*128+d] + gate*ve
// ---------------------------------------------------------------------------
__global__ __launch_bounds__(256) void gate_vt(const ushort* __restrict__ vbuf,
                                               const float* __restrict__ x,
                                               const float* __restrict__ ve,
                                               const float* __restrict__ Wg,
                                               ushort* __restrict__ Vt) {
    const int t0 = blockIdx.x * 64, g = blockIdx.y, b = blockIdx.z;
    __shared__ float gateS[64];
    __shared__ ushort tile[128][66];   // [d][t], padded
    const int tid = threadIdx.x;
    if (tid < 64) {
        const float* xr = x + (size_t)(b * T_ + t0 + tid) * C_;
        float acc = 0.f;
        #pragma unroll
        for (int c = 0; c < 12; c++) acc += xr[c] * Wg[g * 12 + c];
        gateS[tid] = 3.0f / (1.0f + __expf(-acc));
    }
    __syncthreads();
    #pragma unroll
    for (int i = 0; i < 32; i++) {
        int idx = i * 256 + tid;       // 0..8191
        int r = idx >> 7;              // t within tile
        int d = idx & 127;
        size_t offv = (size_t)(b * T_ + t0 + r) * 512 + g * D_ + d;
        tile[d][r] = f2bf(bf2f(vbuf[offv]) + gateS[r] * ve[offv]);
    }
    __syncthreads();
    ushort* ob = Vt + ((size_t)(b * KV_ + g) * D_) * T_ + t0;
    #pragma unroll
    for (int i = 0; i < 32; i++) {
        int idx = i * 256 + tid;
        int d = idx >> 6;              // 0..127
        int c = idx & 63;
        ob[(size_t)d * T_ + c] = tile[d][c];
    }
}

// ---------------------------------------------------------------------------
// Flash attention: block = (b, h, 64 queries), 4 waves x 16 queries.
// ---------------------------------------------------------------------------
__global__ __launch_bounds__(256, 3) void attn_mfma(const ushort* __restrict__ Qp,
                                                    const ushort* __restrict__ Kp,
                                                    const ushort* __restrict__ Vt,
                                                    ushort* __restrict__ Y,
                                                    const int* __restrict__ wptr) {
    const int t0 = blockIdx.x * 64;
    const int h  = blockIdx.y, b = blockIdx.z;
    const int g  = h / REP_;
    const int tid  = threadIdx.x;
    const int wave = tid >> 6, lane = tid & 63;
    const int m16 = lane & 15, quad = lane >> 4;

    __shared__ ushort Ks[4 * 32 * 32];   // 8 KB
    __shared__ ushort Vs[128 * 32];      // 8 KB
    __shared__ ushort Pl[4][16 * 40];    // 5 KB, per-wave P buffers

    const int w = *wptr;
    const bool windowed = (w >= 0 && w < T_);
    const unsigned wu = windowed ? (unsigned)w : 0x7FFFFFFFu;
    int s_lo = 0;
    if (windowed) { s_lo = t0 - w; if (s_lo < 0) s_lo = 0; }
    const int s_hi = t0 + 63;
    const int ss0 = s_lo & ~31;
    const int tw = t0 + wave * 16;

    const ushort* qrow = Qp + ((size_t)(b * H_ + h) * T_ + tw + m16) * D_ + quad * 8;
    bf16x8 qa[4];
    #pragma unroll
    for (int kc = 0; kc < 4; kc++) qa[kc] = ldb8(qrow + kc * 32);

    const ushort* kbase = Kp + (size_t)(b * KV_ + g) * T_ * D_;
    const ushort* vbase = Vt + (size_t)(b * KV_ + g) * D_ * T_;

    const int c0 = wave, c1 = wave + 4;
    const ushort* kg0 = kbase + (size_t)((c0 & 1) * 16 + (lane >> 2)) * D_ + (c0 >> 1) * 32 + (lane & 3) * 8;
    const ushort* kg1 = kbase + (size_t)((c1 & 1) * 16 + (lane >> 2)) * D_ + (c1 >> 1) * 32 + (lane & 3) * 8;
    ushort* kl0 = Ks + c0 * 512;
    ushort* kl1 = Ks + c1 * 512;
    const ushort* vg0 = vbase + (size_t)(c0 * 16 + (lane >> 2)) * T_ + (lane & 3) * 8;
    const ushort* vg1 = vbase + (size_t)(c1 * 16 + (lane >> 2)) * T_ + (lane & 3) * 8;
    ushort* vl0 = Vs + c0 * 512;
    ushort* vl1 = Vs + c1 * 512;

    f32x4 o[8];
    #pragma unroll
    for (int dt = 0; dt < 8; dt++) o[dt] = (f32x4){0.f, 0.f, 0.f, 0.f};
    f32x4 lacc = (f32x4){0.f, 0.f, 0.f, 0.f};
    BCast onesc; onesc.u = (u32x4){0x3F803F80u, 0x3F803F80u, 0x3F803F80u, 0x3F803F80u};
    const bf16x8 ones = onesc.b;
    ushort* pw = &Pl[wave][0];

    for (int ss = ss0; ss <= s_hi; ss += 32) {
        const size_t koff = (size_t)ss * D_;
        async_copy16(kg0 + koff, kl0);
        async_copy16(kg1 + koff, kl1);
        async_copy16(vg0 + ss,   vl0);
        async_copy16(vg1 + ss,   vl1);
        __syncthreads();

        f32x4 s0 = (f32x4){0.f,0.f,0.f,0.f};
        f32x4 s1 = (f32x4){0.f,0.f,0.f,0.f};
        #pragma unroll
        for (int kc = 0; kc < 4; kc++) {
            bf16x8 kf0 = ldb8(Ks + kc * 1024 + m16 * 32 + quad * 8);
            bf16x8 kf1 = ldb8(Ks + kc * 1024 + (16 + m16) * 32 + quad * 8);
            s0 = __builtin_amdgcn_mfma_f32_16x16x32_bf16(qa[kc], kf0, s0, 0, 0, 0);
            s1 = __builtin_amdgcn_mfma_f32_16x16x32_bf16(qa[kc], kf1, s1, 0, 0, 0);
        }

        const int sA = ss + m16, sB = ss + 16 + m16;
        #pragma unroll
        for (int reg = 0; reg < 4; reg++) {
            const int t = tw + quad * 4 + reg;
            const float pa = ((unsigned)(t - sA) <= wu) ? __expf(s0[reg]) : 0.f;
            const float pb = ((unsigned)(t - sB) <= wu) ? __expf(s1[reg]) : 0.f;
            pw[(quad * 4 + reg) * 40 + m16]      = f2bf(pa);
            pw[(quad * 4 + reg) * 40 + 16 + m16] = f2bf(pb);
        }

        __builtin_amdgcn_s_waitcnt(0xc07f);   // lgkmcnt(0), leave vmcnt alone
        bf16x8 pfrag = ldb8(pw + m16 * 40 + quad * 8);

        #pragma unroll
        for (int dt = 0; dt < 8; dt++) {
            bf16x8 vf = ldb8(Vs + (dt * 16 + m16) * 32 + quad * 8);
            o[dt] = __builtin_amdgcn_mfma_f32_16x16x32_bf16(pfrag, vf, o[dt], 0, 0, 0);
        }
        lacc = __builtin_amdgcn_mfma_f32_16x16x32_bf16(pfrag, ones, lacc, 0, 0, 0);
        __syncthreads();
    }

    float inv[4];
    #pragma unroll
    for (int reg = 0; reg < 4; reg++) inv[reg] = 1.0f / lacc[reg];
    ushort* yb = Y + ((size_t)(b * T_ + tw + quad * 4) * H_ + h) * D_ + m16;
    #pragma unroll
    for (int reg = 0; reg < 4; reg++)
        #pragma unroll
        for (int dt = 0; dt < 8; dt++)
            yb[(size_t)reg * H_ * D_ + dt * 16] = f2bf(o[dt][reg] * inv[reg]);
}

// ---------------------------------------------------------------------------
extern "C" void kernel_launch(void* const* d_in, const int* in_sizes, int n_in,
                              void* d_out, int out_size, void* d_ws, size_t ws_size,
                              hipStream_t stream) {
    const float* x     = (const float*)d_in[0];
    const float* ve    = (const float*)d_in[1];
    const float* cosb  = (const float*)d_in[2];
    const float* sinb  = (const float*)d_in[3];
    const float* Wq    = (const float*)d_in[4];
    const float* Wk    = (const float*)d_in[5];
    const float* Wv    = (const float*)d_in[6];
    const float* Wproj = (const float*)d_in[7];
    const float* Wg    = (const float*)d_in[8];
    const int*   wptr  = (const int*)d_in[9];
    float* out = (float*)d_out;

    // workspace layout (all bf16/ushort), ~63 MB
    ushort* xb    = (ushort*)d_ws;                    // M*C
    ushort* vbuf  = xb    + (size_t)M_ * C_;          // M*512
    ushort* Qp    = vbuf  + (size_t)M_ * 512;         // M*C (permuted d)
    ushort* Kp    = Qp    + (size_t)M_ * C_;          // M*512 (permuted d)
    ushort* Vt    = Kp    + (size_t)M_ * 512;         // M*512
    ushort* yb16  = Vt    + (size_t)M_ * 512;         // M*C
    ushort* Wqkvb = yb16  + (size_t)M_ * C_;          // 2560*C (q/k rows dperm'd)
    ushort* Wpb   = Wqkvb + (size_t)NQKV_ * C_;       // C*C

    cast_all<<<SEG4 / 256, 256, 0, stream>>>(x, Wq, Wk, Wv, Wproj, xb, Wqkvb, Wpb);

    gemm256<0><<<dim3(NQKV_ / 256, M_ / 256), 512, 0, stream>>>(
        xb, Wqkvb, Qp, Kp, vbuf, nullptr, cosb, sinb);

    gate_vt<<<dim3(T_ / 64, KV_, B_), 256, 0, stream>>>(vbuf, x, ve, Wg, Vt);

    attn_mfma<<<dim3(T_ / 64, H_, B_), 256, 0, stream>>>(Qp, Kp, Vt, yb16, wptr);

    gemm256<1><<<dim3(C_ / 256, M_ / 256), 512, 0, stream>>>(
        yb16, Wpb, nullptr, nullptr, nullptr, out, nullptr, nullptr);
}

// Round 5
// 263.397 us; speedup vs baseline: 3.0607x; 1.0223x over previous
//
#include <hip/hip_runtime.h>
#include <hip/hip_bf16.h>
#include <math.h>

// Problem constants
#define B_  2
#define T_  2048
#define C_  1536
#define H_  12
#define KV_ 4
#define D_  128
#define M_  (B_*T_)   // 4096 rows
#define REP_ (H_/KV_) // 3
#define NQKV_ 2560    // fused q|k|v output width
#define KK_  1536     // K for both big GEMMs
#define NKT_ 24       // KK_/64 K-tiles

typedef __bf16 bf16x8 __attribute__((ext_vector_type(8)));
typedef float  f32x4  __attribute__((ext_vector_type(4)));
typedef unsigned u32x4 __attribute__((ext_vector_type(4)));

union BCast { u32x4 u; bf16x8 b; };

__device__ inline bf16x8 ldb8(const ushort* p) {
    BCast c; c.u = *reinterpret_cast<const u32x4*>(p); return c.b;
}

__device__ inline ushort f2bf(float f) {
    union { float f; unsigned u; } v; v.f = f;
    unsigned u = v.u;
    return (ushort)((u + 0x7FFF + ((u >> 16) & 1)) >> 16);
}

__device__ inline float bf2f(ushort u) {
    union { unsigned u; float f; } v; v.u = (unsigned)u << 16;
    return v.f;
}

// async global->LDS, 16 bytes per lane; lds base must be wave-uniform
__device__ inline void async_copy16(const ushort* g, ushort* l) {
    __builtin_amdgcn_global_load_lds(
        (const __attribute__((address_space(1))) unsigned*)g,
        (__attribute__((address_space(3))) unsigned*)l, 16, 0, 0);
}

// d-permutation for rope-pair locality: swap middle two 32-blocks of each head.
__device__ __host__ inline int dperm(int d) {
    return (d < 32) ? d : (d < 64 ? d + 32 : (d < 96 ? d - 32 : d));
}

#define MFMA16(va, vb, d) d = __builtin_amdgcn_mfma_f32_16x16x32_bf16(va, vb, d, 0, 0, 0)

// NOTE (r1/r2/r4 lesson): the K-tile body is ONE straight-line region with NO
// barriers/fences inside — hipcc pipelines the 24 ds_reads under the MFMA
// clusters with counted lgkmcnt itself (m97 asm evidence). Any mid-tile
// s_barrier pins reads/MFMAs into serial epochs (r1/r2/r4 all ~same perf);
// manual cross-tile register rings spill (r3). Hand-placed sync is ONLY at
// the double-buffer handoff: Bar1 -> stage -> counted vmcnt -> Bar2.
#define CLUSTER(AARR, BARR, MB, NB)                                        \
    __builtin_amdgcn_s_setprio(1);                                         \
    _Pragma("unroll")                                                      \
    for (int mf = 0; mf < 4; mf++)                                         \
        _Pragma("unroll")                                                  \
        for (int nf = 0; nf < 2; nf++) {                                   \
            MFMA16(AARR[mf*2+0], BARR[nf*2+0], acc[(MB)+mf][(NB)+nf]);     \
            MFMA16(AARR[mf*2+1], BARR[nf*2+1], acc[(MB)+mf][(NB)+nf]);     \
        }                                                                  \
    __builtin_amdgcn_s_setprio(0);

#define RD_A(rb, boA_) { _Pragma("unroll") for (int mf = 0; mf < 4; mf++) { \
        a[rb][mf*2+0] = ldb8(aB0 + (boA_) + (rb)*4096 + mf*1024);           \
        a[rb][mf*2+1] = ldb8(aB1 + (boA_) + (rb)*4096 + mf*1024); } }
#define RD_B0(boB_) { _Pragma("unroll") for (int nf = 0; nf < 2; nf++) {    \
        b0[nf*2+0] = ldb8(bB0 + (boB_) + nf*1024);                          \
        b0[nf*2+1] = ldb8(bB1 + (boB_) + nf*1024); } }
#define RD_B1(boB_) { _Pragma("unroll") for (int nf = 0; nf < 2; nf++) {    \
        b1[nf*2+0] = ldb8(bB0 + (boB_) + 2048 + nf*1024);                   \
        b1[nf*2+1] = ldb8(bB1 + (boB_) + 2048 + nf*1024); } }

// ---------------------------------------------------------------------------
// BMx256 GEMM (BM in {128,256}): C[M,N] = A[M,K]*B[N,K]^T. 512 thr / 8 waves
// (2M x 4N); wave tile (BM/2)x64 = acc[BM/32][4] f32x4. BK=64.
// LDS: A 2buf x [2 halves][BM/2 x 64], B 2buf x [2 halves][128 x 64],
// XOR-swizzled (both-sides, rule 21). Free-running K-tile body + 2-barrier
// handoff with counted vmcnt (loads-per-tile L = 4 + 2*RB stay in flight).
// EPI 0 = qkv (BM=256: rope/rms q,k | v->vbuf), EPI 1 = fp32 C (proj, BM=128
// for grid fill: 192 blocks vs 96).
// ---------------------------------------------------------------------------
template<int EPI, int BM>
__global__ __launch_bounds__(512) void gemm256(const ushort* __restrict__ A,
                                               const ushort* __restrict__ Bm,
                                               ushort* __restrict__ Qp,
                                               ushort* __restrict__ Kp,
                                               ushort* __restrict__ vbuf,
                                               float* __restrict__ Cf,
                                               const float* __restrict__ cosb,
                                               const float* __restrict__ sinb) {
    constexpr int RB = BM / 128;          // A row-blocks per wave (1 or 2)
    constexpr int MF = BM / 32;           // acc M-frags (4 or 8)
    constexpr int AH = BM * 32;           // A half size in ushorts
    constexpr int L  = 4 + 2 * RB;        // staging loads per K-tile per wave
    constexpr unsigned VM_L = 0x0F70u | L;
    __shared__ ushort ldsA[2 * 2 * AH];
    __shared__ ushort ldsB[2 * 2 * 8192];
    const int tid  = threadIdx.x;
    const int wave = tid >> 6, lane = tid & 63;
    const int m16 = lane & 15, quad = lane >> 4;
    const int WM = wave >> 2, WN = wave & 3;
    const int brow = (WN & 1) << 6;

    // XCD-aware bijective remap, M-fastest within each XCD chunk.
    const int nwg  = gridDim.x * gridDim.y;
    const int orig = blockIdx.y * gridDim.x + blockIdx.x;
    const int vid  = (orig & 7) * (nwg >> 3) + (orig >> 3);
    const int gy   = gridDim.y;
    const int bxT  = vid / gy;
    const int byT  = vid - bxT * gy;
    const int bm = byT * BM, bn = bxT << 8;

    // staging: linear LDS dest, inverse-swizzled global source (rule 21)
    const int r = tid >> 3;                              // 0..63
    const int slot8 = ((tid & 7) ^ (r & 7)) << 3;        // swizzled col (elems)
    const ushort* Ag = A  + (size_t)(bm + r) * KK_ + slot8;
    const ushort* Bg = Bm + (size_t)(bn + r) * KK_ + slot8;
    const size_t row64 = (size_t)64 * KK_;
    const size_t hskip = (size_t)128 * KK_;

    auto stageB4 = [&](int buf, int kc) {
        ushort* base = ldsB + buf * 16384 + wave * 512;
        const ushort* g = Bg + kc;
        async_copy16(g,                 base);
        async_copy16(g + row64,         base + 4096);
        async_copy16(g + hskip,         base + 8192);
        async_copy16(g + hskip + row64, base + 8192 + 4096);
    };
    auto stageA = [&](int buf, int kc) {
        ushort* base = ldsA + buf * (2 * AH) + wave * 512;
        const ushort* g = Ag + kc;
        async_copy16(g,         base);
        async_copy16(g + row64, base + 4096);
        if constexpr (RB == 2) {
            async_copy16(g + hskip,         base + 8192);
            async_copy16(g + hskip + row64, base + 8192 + 4096);
        }
    };

    // per-lane swizzled frag base pointers; byte swizzle: bits4..6 ^= row&7.
    const int swzu = (m16 & 7) << 3;
    const int k0u  = (quad * 8) ^ swzu;
    const int k1u  = (32 + quad * 8) ^ swzu;
    const ushort* aB0 = ldsA + WM * AH + (m16 << 6) + k0u;
    const ushort* aB1 = ldsA + WM * AH + (m16 << 6) + k1u;
    const ushort* bB0 = ldsB + ((WN >> 1) ? 8192 : 0) + ((brow + m16) << 6) + k0u;
    const ushort* bB1 = ldsB + ((WN >> 1) ? 8192 : 0) + ((brow + m16) << 6) + k1u;

    f32x4 acc[MF][4];
    #pragma unroll
    for (int i = 0; i < MF; i++)
        #pragma unroll
        for (int j = 0; j < 4; j++) acc[i][j] = (f32x4){0.f, 0.f, 0.f, 0.f};

    // prologue: stage K-tiles 0 (buf0) and 1 (buf1); certify tile0
    stageB4(0, 0);  stageA(0, 0);
    stageB4(1, 64); stageA(1, 64);
    __builtin_amdgcn_s_waitcnt(VM_L);     // vmcnt(L): tile0 landed
    __builtin_amdgcn_sched_barrier(0);
    __builtin_amdgcn_s_barrier();
    __builtin_amdgcn_sched_barrier(0);

    #pragma unroll 1
    for (int kt = 0; kt < NKT_; kt++) {
        const int boA = (kt & 1) ? 2 * AH : 0;
        const int boB = (kt & 1) ? 16384 : 0;
        bf16x8 a[2][8], b0[4], b1[4];
        // one straight-line region: compiler interleaves reads & MFMAs with
        // counted lgkm waits (no barriers, no fences inside).
        RD_A(0, boA); RD_B0(boB); RD_B1(boB);
        if constexpr (RB == 2) RD_A(1, boA);
        CLUSTER(a[0], b0, 0, 0);
        CLUSTER(a[0], b1, 0, 2);
        if constexpr (RB == 2) {
            CLUSTER(a[1], b1, 4, 2);
            CLUSTER(a[1], b0, 4, 0);
        }
        if (kt < NKT_ - 1) {
            __builtin_amdgcn_sched_barrier(0);
            __builtin_amdgcn_s_barrier();      // Bar1: cur buf read-complete
            __builtin_amdgcn_sched_barrier(0);
            if (kt < NKT_ - 2) {
                stageB4(kt & 1, (kt + 2) << 6);
                stageA(kt & 1, (kt + 2) << 6);
                __builtin_amdgcn_s_waitcnt(VM_L);    // vmcnt(L): kt+1 landed
            } else {
                __builtin_amdgcn_s_waitcnt(0x0F70);  // vmcnt(0): drain tail
            }
            __builtin_amdgcn_sched_barrier(0);
            __builtin_amdgcn_s_barrier();      // Bar2: nxt buf certified
            __builtin_amdgcn_sched_barrier(0);
        }
    }
    __syncthreads();   // quiesce before epilogue LDS reuse

    // ---------------- epilogues ----------------
    if constexpr (EPI == 0) {
        if (bn >= 2048) {
            // v tile: plain bf16 to vbuf [row][512] (original d-order)
            const int cb = bn - 2048 + WN*64;
            #pragma unroll
            for (int m = 0; m < MF; m++) {
                const int rl = WM*(BM/2) + (m>>2)*64 + (m&3)*16 + quad*4;
                #pragma unroll
                for (int reg = 0; reg < 4; reg++) {
                    ushort* vr = vbuf + (size_t)(bm + rl + reg) * 512 + cb + m16;
                    #pragma unroll
                    for (int j = 0; j < 4; j++)
                        vr[(j>>1)*32 + (j&1)*16] = f2bf(acc[m][j][reg]);
                }
            }
        } else {
            // q/k tile: RMS (rotation-invariant, from raw acc) + rope
            float* ssqS = (float*)ldsA;   // 4KB scratch
            #pragma unroll
            for (int m = 0; m < MF; m++) {
                #pragma unroll
                for (int reg = 0; reg < 4; reg++) {
                    float v = acc[m][0][reg]*acc[m][0][reg] + acc[m][1][reg]*acc[m][1][reg]
                            + acc[m][2][reg]*acc[m][2][reg] + acc[m][3][reg]*acc[m][3][reg];
                    v += __shfl_xor(v, 1); v += __shfl_xor(v, 2);
                    v += __shfl_xor(v, 4); v += __shfl_xor(v, 8);
                    if (m16 == 0) {
                        const int rl = WM*(BM/2) + (m>>2)*64 + (m&3)*16 + quad*4 + reg;
                        ssqS[rl*4 + WN] = v;   // wave's 64-col partial
                    }
                }
            }
            __syncthreads();

            const bool isq = (bn < 1536);
            const float osc = isq ? (1.2f * 1.2f * 0.08838834764831845f) : 1.0f;
            const int hh = (isq ? (bn >> 7) : ((bn - 1536) >> 7)) + (WN >> 1);
            const int nh  = isq ? H_ : KV_;
            ushort* outp  = isq ? Qp : Kp;

            #pragma unroll
            for (int m = 0; m < MF; m++) {
                #pragma unroll
                for (int reg = 0; reg < 4; reg++) {
                    const int rl = WM*(BM/2) + (m>>2)*64 + (m&3)*16 + quad*4 + reg;
                    const int row = bm + rl;
                    const float tot = ssqS[rl*4 + (WN & ~1)] + ssqS[rl*4 + (WN | 1)];
                    const float sc = rsqrtf(tot * (1.0f/128.0f) + 1.1920928955078125e-07f) * osc;
                    const int b = row >> 11, t = row & (T_ - 1);
                    ushort* orow = outp + ((size_t)(b * nh + hh) * T_ + t) * D_;
                    #pragma unroll
                    for (int nf = 0; nf < 2; nf++) {
                        const int ipair = (WN & 1) * 32 + nf*16 + m16;
                        const float c = cosb[t*64 + ipair], s = sinb[t*64 + ipair];
                        const float x1 = acc[m][nf][reg], x2 = acc[m][2+nf][reg];
                        const int oc = (WN & 1) * 64 + nf*16 + m16;
                        orow[oc]      = f2bf((x1*c + x2*s) * sc);
                        orow[oc + 32] = f2bf((x2*c - x1*s) * sc);
                    }
                }
            }
        }
    } else {
        // plain fp32 C
        #pragma unroll
        for (int m = 0; m < MF; m++) {
            const int rl = WM*(BM/2) + (m>>2)*64 + (m&3)*16 + quad*4;
            #pragma unroll
            for (int reg = 0; reg < 4; reg++) {
                float* cr = Cf + (size_t)(bm + rl + reg) * C_ + bn + WN*64 + m16;
                #pragma unroll
                for (int j = 0; j < 4; j++)
                    cr[(j>>1)*32 + (j&1)*16] = acc[m][j][reg];
            }
        }
    }
}

// ---------------------------------------------------------------------------
// Fused segmented fp32->bf16 cast of x, Wq, Wk, Wv, Wproj (one launch).
// ---------------------------------------------------------------------------
#define SEG0 1572864   // x      : 4096*1536/4
#define SEG1 2162688   // + Wq   : 1536*1536/4
#define SEG2 2359296   // + Wk   : 512*1536/4
#define SEG3 2555904   // + Wv   : 512*1536/4
#define SEG4 3145728   // + Wproj: 1536*1536/4
#define ROW4 384       // float4s per 1536-col row
__global__ __launch_bounds__(256) void cast_all(const float* __restrict__ x,
                                                const float* __restrict__ Wq,
                                                const float* __restrict__ Wk,
                                                const float* __restrict__ Wv,
                                                const float* __restrict__ Wp,
                                                ushort* __restrict__ xb,
                                                ushort* __restrict__ Wqkvb,
                                                ushort* __restrict__ Wpb) {
    const int i = blockIdx.x * 256 + threadIdx.x;
    float4 v; size_t dst4; ushort* dstp;
    if (i < SEG0) {
        v = ((const float4*)x)[i]; dstp = xb; dst4 = i;
    } else if (i < SEG1) {
        const int j = i - SEG0;
        const int r = j / ROW4, c4 = j - r * ROW4;
        const int d = r & 127, hh = r >> 7;
        v = ((const float4*)Wq)[j]; dstp = Wqkvb;
        dst4 = (size_t)(hh * 128 + dperm(d)) * ROW4 + c4;
    } else if (i < SEG2) {
        const int j = i - SEG1;
        const int r = j / ROW4, c4 = j - r * ROW4;
        const int d = r & 127, g = r >> 7;
        v = ((const float4*)Wk)[j]; dstp = Wqkvb;
        dst4 = (size_t)(1536 + g * 128 + dperm(d)) * ROW4 + c4;
    } else if (i < SEG3) {
        const int j = i - SEG2;
        v = ((const float4*)Wv)[j]; dstp = Wqkvb;
        dst4 = (size_t)2048 * ROW4 + j;
    } else {
        const int j = i - SEG3;
        v = ((const float4*)Wp)[j]; dstp = Wpb; dst4 = j;
    }
    ((ushort4*)dstp)[dst4] = make_ushort4(f2bf(v.x), f2bf(v.y), f2bf(v.z), f2bf(v.w));
}

// ---------------------------------------------------------------------------
// Fused ve-gate + transpose: Vt[b][g][d][s] = vbuf[bt][g*128+d] + gate*ve
// ---------------------------------------------------------------------------
__global__ __launch_bounds__(256) void gate_vt(const ushort* __restrict__ vbuf,
                                               const float* __restrict__ x,
                                               const float* __restrict__ ve,
                                               const float* __restrict__ Wg,
                                               ushort* __restrict__ Vt) {
    const int t0 = blockIdx.x * 64, g = blockIdx.y, b = blockIdx.z;
    __shared__ float gateS[64];
    __shared__ ushort tile[128][66];   // [d][t], padded
    const int tid = threadIdx.x;
    if (tid < 64) {
        const float* xr = x + (size_t)(b * T_ + t0 + tid) * C_;
        float acc = 0.f;
        #pragma unroll
        for (int c = 0; c < 12; c++) acc += xr[c] * Wg[g * 12 + c];
        gateS[tid] = 3.0f / (1.0f + __expf(-acc));
    }
    __syncthreads();
    #pragma unroll
    for (int i = 0; i < 32; i++) {
        int idx = i * 256 + tid;       // 0..8191
        int r = idx >> 7;              // t within tile
        int d = idx & 127;
        size_t offv = (size_t)(b * T_ + t0 + r) * 512 + g * D_ + d;
        tile[d][r] = f2bf(bf2f(vbuf[offv]) + gateS[r] * ve[offv]);
    }
    __syncthreads();
    ushort* ob = Vt + ((size_t)(b * KV_ + g) * D_) * T_ + t0;
    #pragma unroll
    for (int i = 0; i < 32; i++) {
        int idx = i * 256 + tid;
        int d = idx >> 6;              // 0..127
        int c = idx & 63;
        ob[(size_t)d * T_ + c] = tile[d][c];
    }
}

// ---------------------------------------------------------------------------
// Flash attention: block = (b, h, 64 queries), 4 waves x 16 queries.
// ---------------------------------------------------------------------------
__global__ __launch_bounds__(256, 3) void attn_mfma(const ushort* __restrict__ Qp,
                                                    const ushort* __restrict__ Kp,
                                                    const ushort* __restrict__ Vt,
                                                    ushort* __restrict__ Y,
                                                    const int* __restrict__ wptr) {
    const int t0 = blockIdx.x * 64;
    const int h  = blockIdx.y, b = blockIdx.z;
    const int g  = h / REP_;
    const int tid  = threadIdx.x;
    const int wave = tid >> 6, lane = tid & 63;
    const int m16 = lane & 15, quad = lane >> 4;

    __shared__ ushort Ks[4 * 32 * 32];   // 8 KB
    __shared__ ushort Vs[128 * 32];      // 8 KB
    __shared__ ushort Pl[4][16 * 40];    // 5 KB, per-wave P buffers

    const int w = *wptr;
    const bool windowed = (w >= 0 && w < T_);
    const unsigned wu = windowed ? (unsigned)w : 0x7FFFFFFFu;
    int s_lo = 0;
    if (windowed) { s_lo = t0 - w; if (s_lo < 0) s_lo = 0; }
    const int s_hi = t0 + 63;
    const int ss0 = s_lo & ~31;
    const int tw = t0 + wave * 16;

    const ushort* qrow = Qp + ((size_t)(b * H_ + h) * T_ + tw + m16) * D_ + quad * 8;
    bf16x8 qa[4];
    #pragma unroll
    for (int kc = 0; kc < 4; kc++) qa[kc] = ldb8(qrow + kc * 32);

    const ushort* kbase = Kp + (size_t)(b * KV_ + g) * T_ * D_;
    const ushort* vbase = Vt + (size_t)(b * KV_ + g) * D_ * T_;

    const int c0 = wave, c1 = wave + 4;
    const ushort* kg0 = kbase + (size_t)((c0 & 1) * 16 + (lane >> 2)) * D_ + (c0 >> 1) * 32 + (lane & 3) * 8;
    const ushort* kg1 = kbase + (size_t)((c1 & 1) * 16 + (lane >> 2)) * D_ + (c1 >> 1) * 32 + (lane & 3) * 8;
    ushort* kl0 = Ks + c0 * 512;
    ushort* kl1 = Ks + c1 * 512;
    const ushort* vg0 = vbase + (size_t)(c0 * 16 + (lane >> 2)) * T_ + (lane & 3) * 8;
    const ushort* vg1 = vbase + (size_t)(c1 * 16 + (lane >> 2)) * T_ + (lane & 3) * 8;
    ushort* vl0 = Vs + c0 * 512;
    ushort* vl1 = Vs + c1 * 512;

    f32x4 o[8];
    #pragma unroll
    for (int dt = 0; dt < 8; dt++) o[dt] = (f32x4){0.f, 0.f, 0.f, 0.f};
    f32x4 lacc = (f32x4){0.f, 0.f, 0.f, 0.f};
    BCast onesc; onesc.u = (u32x4){0x3F803F80u, 0x3F803F80u, 0x3F803F80u, 0x3F803F80u};
    const bf16x8 ones = onesc.b;
    ushort* pw = &Pl[wave][0];

    for (int ss = ss0; ss <= s_hi; ss += 32) {
        const size_t koff = (size_t)ss * D_;
        async_copy16(kg0 + koff, kl0);
        async_copy16(kg1 + koff, kl1);
        async_copy16(vg0 + ss,   vl0);
        async_copy16(vg1 + ss,   vl1);
        __syncthreads();

        f32x4 s0 = (f32x4){0.f,0.f,0.f,0.f};
        f32x4 s1 = (f32x4){0.f,0.f,0.f,0.f};
        #pragma unroll
        for (int kc = 0; kc < 4; kc++) {
            bf16x8 kf0 = ldb8(Ks + kc * 1024 + m16 * 32 + quad * 8);
            bf16x8 kf1 = ldb8(Ks + kc * 1024 + (16 + m16) * 32 + quad * 8);
            s0 = __builtin_amdgcn_mfma_f32_16x16x32_bf16(qa[kc], kf0, s0, 0, 0, 0);
            s1 = __builtin_amdgcn_mfma_f32_16x16x32_bf16(qa[kc], kf1, s1, 0, 0, 0);
        }

        const int sA = ss + m16, sB = ss + 16 + m16;
        #pragma unroll
        for (int reg = 0; reg < 4; reg++) {
            const int t = tw + quad * 4 + reg;
            const float pa = ((unsigned)(t - sA) <= wu) ? __expf(s0[reg]) : 0.f;
            const float pb = ((unsigned)(t - sB) <= wu) ? __expf(s1[reg]) : 0.f;
            pw[(quad * 4 + reg) * 40 + m16]      = f2bf(pa);
            pw[(quad * 4 + reg) * 40 + 16 + m16] = f2bf(pb);
        }

        __builtin_amdgcn_s_waitcnt(0xc07f);   // lgkmcnt(0), leave vmcnt alone
        bf16x8 pfrag = ldb8(pw + m16 * 40 + quad * 8);

        #pragma unroll
        for (int dt = 0; dt < 8; dt++) {
            bf16x8 vf = ldb8(Vs + (dt * 16 + m16) * 32 + quad * 8);
            o[dt] = __builtin_amdgcn_mfma_f32_16x16x32_bf16(pfrag, vf, o[dt], 0, 0, 0);
        }
        lacc = __builtin_amdgcn_mfma_f32_16x16x32_bf16(pfrag, ones, lacc, 0, 0, 0);
        __syncthreads();
    }

    float inv[4];
    #pragma unroll
    for (int reg = 0; reg < 4; reg++) inv[reg] = 1.0f / lacc[reg];
    ushort* yb = Y + ((size_t)(b * T_ + tw + quad * 4) * H_ + h) * D_ + m16;
    #pragma unroll
    for (int reg = 0; reg < 4; reg++)
        #pragma unroll
        for (int dt = 0; dt < 8; dt++)
            yb[(size_t)reg * H_ * D_ + dt * 16] = f2bf(o[dt][reg] * inv[reg]);
}

// ---------------------------------------------------------------------------
extern "C" void kernel_launch(void* const* d_in, const int* in_sizes, int n_in,
                              void* d_out, int out_size, void* d_ws, size_t ws_size,
                              hipStream_t stream) {
    const float* x     = (const float*)d_in[0];
    const float* ve    = (const float*)d_in[1];
    const float* cosb  = (const float*)d_in[2];
    const float* sinb  = (const float*)d_in[3];
    const float* Wq    = (const float*)d_in[4];
    const float* Wk    = (const float*)d_in[5];
    const float* Wv    = (const float*)d_in[6];
    const float* Wproj = (const float*)d_in[7];
    const float* Wg    = (const float*)d_in[8];
    const int*   wptr  = (const int*)d_in[9];
    float* out = (float*)d_out;

    // workspace layout (all bf16/ushort), ~63 MB
    ushort* xb    = (ushort*)d_ws;                    // M*C
    ushort* vbuf  = xb    + (size_t)M_ * C_;          // M*512
    ushort* Qp    = vbuf  + (size_t)M_ * 512;         // M*C (permuted d)
    ushort* Kp    = Qp    + (size_t)M_ * C_;          // M*512 (permuted d)
    ushort* Vt    = Kp    + (size_t)M_ * 512;         // M*512
    ushort* yb16  = Vt    + (size_t)M_ * 512;         // M*C
    ushort* Wqkvb = yb16  + (size_t)M_ * C_;          // 2560*C (q/k rows dperm'd)
    ushort* Wpb   = Wqkvb + (size_t)NQKV_ * C_;       // C*C

    cast_all<<<SEG4 / 256, 256, 0, stream>>>(x, Wq, Wk, Wv, Wproj, xb, Wqkvb, Wpb);

    gemm256<0, 256><<<dim3(NQKV_ / 256, M_ / 256), 512, 0, stream>>>(
        xb, Wqkvb, Qp, Kp, vbuf, nullptr, cosb, sinb);

    gate_vt<<<dim3(T_ / 64, KV_, B_), 256, 0, stream>>>(vbuf, x, ve, Wg, Vt);

    attn_mfma<<<dim3(T_ / 64, H_, B_), 256, 0, stream>>>(Qp, Kp, Vt, yb16, wptr);

    gemm256<1, 128><<<dim3(C_ / 256, M_ / 128), 512, 0, stream>>>(
        yb16, Wpb, nullptr, nullptr, nullptr, out, nullptr, nullptr);
}

// Round 6
// 258.547 us; speedup vs baseline: 3.1181x; 1.0188x over previous
//
#include <hip/hip_runtime.h>
#include <hip/hip_bf16.h>
#include <math.h>

// Problem constants
#define B_  2
#define T_  2048
#define C_  1536
#define H_  12
#define KV_ 4
#define D_  128
#define M_  (B_*T_)   // 4096 rows
#define REP_ (H_/KV_) // 3
#define NQKV_ 2560    // fused q|k|v output width
#define KK_  1536     // K for both big GEMMs
#define NKT_ 24       // KK_/64 K-tiles

typedef __bf16 bf16x8 __attribute__((ext_vector_type(8)));
typedef float  f32x4  __attribute__((ext_vector_type(4)));
typedef unsigned u32x4 __attribute__((ext_vector_type(4)));

union BCast { u32x4 u; bf16x8 b; };

__device__ inline bf16x8 ldb8(const ushort* p) {
    BCast c; c.u = *reinterpret_cast<const u32x4*>(p); return c.b;
}

__device__ inline ushort f2bf(float f) {
    union { float f; unsigned u; } v; v.f = f;
    unsigned u = v.u;
    return (ushort)((u + 0x7FFF + ((u >> 16) & 1)) >> 16);
}

__device__ inline float bf2f(ushort u) {
    union { unsigned u; float f; } v; v.u = (unsigned)u << 16;
    return v.f;
}

// async global->LDS, 16 bytes per lane; lds base must be wave-uniform
__device__ inline void async_copy16(const ushort* g, ushort* l) {
    __builtin_amdgcn_global_load_lds(
        (const __attribute__((address_space(1))) unsigned*)g,
        (__attribute__((address_space(3))) unsigned*)l, 16, 0, 0);
}

// d-permutation for rope-pair locality: swap middle two 32-blocks of each head.
__device__ __host__ inline int dperm(int d) {
    return (d < 32) ? d : (d < 64 ? d + 32 : (d < 96 ? d - 32 : d));
}

#define MFMA16(va, vb, d) d = __builtin_amdgcn_mfma_f32_16x16x32_bf16(va, vb, d, 0, 0, 0)

// ---------------------------------------------------------------------------
// 128x128 GEMM, 2 blocks/CU: C[M,N] = A[M,K]*B[N,K]^T.
// STRUCTURE LESSON (r1-r5): a 256^2 1-block/CU tile is epoch-serialized no
// matter how the source schedules it (8 waves barrier-resync each tile; LDS
// read epoch then MFMA epoch; ~6,600 cyc/K-tile across five schedule
// variants). The m97/m114 mechanism that actually overlaps pipes is
// CO-RESIDENT BLOCKS: different blocks share no barrier, so one block's MFMA
// epoch hides the other's LDS epoch. 64 KB LDS => 2 blocks/CU.
// 256 thr / 4 waves (2M x 2N); wave tile 64x64 = acc[4][4] f32x4. BK=64.
// LDS: 2buf x [128][64] per op, XOR-swizzled (both-sides, rule 21), staged
// via global_load_lds w=16. Handoff: Bar1 -> stage kt+2 -> vmcnt(8) -> Bar2
// (counted, never 0 mid-loop). EPI 0 = qkv (rope/rms q,k | v->vbuf; each
// q/k tile is exactly one head), EPI 1 = fp32 C.
// ---------------------------------------------------------------------------
template<int EPI>
__global__ __launch_bounds__(256, 2) void gemm128(const ushort* __restrict__ A,
                                                  const ushort* __restrict__ Bm,
                                                  ushort* __restrict__ Qp,
                                                  ushort* __restrict__ Kp,
                                                  ushort* __restrict__ vbuf,
                                                  float* __restrict__ Cf,
                                                  const float* __restrict__ cosb,
                                                  const float* __restrict__ sinb) {
    __shared__ ushort ldsA[2][8192];   // [buf][128 rows x 64 cols]
    __shared__ ushort ldsB[2][8192];
    const int tid  = threadIdx.x;
    const int wave = tid >> 6, lane = tid & 63;
    const int m16 = lane & 15, quad = lane >> 4;
    const int WM = wave >> 1, WN = wave & 1;

    // XCD-aware bijective remap, M-fastest within each XCD chunk (B-panel
    // L2 reuse). nwg % 8 == 0 for both grids (640, 384).
    const int nwg  = gridDim.x * gridDim.y;
    const int orig = blockIdx.y * gridDim.x + blockIdx.x;
    const int vid  = (orig & 7) * (nwg >> 3) + (orig >> 3);
    const int gy   = gridDim.y;            // 32
    const int bxT  = vid / gy;
    const int byT  = vid - bxT * gy;
    const int bm = byT << 7, bn = bxT << 7;

    // staging: linear LDS dest, inverse-swizzled global source (rule 21).
    // thread tid covers 16B at LDS byte tid*16 per 4KB round; 4 rounds/tile.
    const int r = tid >> 3;                              // 0..31
    const int slot8 = ((tid & 7) ^ (r & 7)) << 3;        // swizzled col (elems)
    const ushort* Ag = A  + (size_t)(bm + r) * KK_ + slot8;
    const ushort* Bg = Bm + (size_t)(bn + r) * KK_ + slot8;
    const size_t row32 = (size_t)32 * KK_;

    auto stage = [&](const ushort* Gp, ushort* ldsOp, int kc) {
        ushort* base = ldsOp + wave * 512;   // wave-uniform, lanes add 16B
        const ushort* g = Gp + kc;
        async_copy16(g,             base);            // rows  0..31 (this wave's 8)
        async_copy16(g +   row32,   base + 2048);     // rows 32..63
        async_copy16(g + 2*row32,   base + 4096);     // rows 64..95
        async_copy16(g + 3*row32,   base + 6144);     // rows 96..127
    };

    // per-lane swizzled frag base pointers; byte swizzle: bits4..6 ^= row&7.
    const int swzu = (m16 & 7) << 3;
    const int k0u  = (quad * 8) ^ swzu;
    const int k1u  = (32 + quad * 8) ^ swzu;
    const ushort* aB0 = &ldsA[0][0] + ((WM * 64 + m16) << 6) + k0u;
    const ushort* aB1 = &ldsA[0][0] + ((WM * 64 + m16) << 6) + k1u;
    const ushort* bB0 = &ldsB[0][0] + ((WN * 64 + m16) << 6) + k0u;
    const ushort* bB1 = &ldsB[0][0] + ((WN * 64 + m16) << 6) + k1u;

    f32x4 acc[4][4];
    #pragma unroll
    for (int i = 0; i < 4; i++)
        #pragma unroll
        for (int j = 0; j < 4; j++) acc[i][j] = (f32x4){0.f, 0.f, 0.f, 0.f};

    // prologue: stage K-tiles 0 (buf0) and 1 (buf1); certify tile0
    stage(Bg, ldsB[0], 0);  stage(Ag, ldsA[0], 0);
    stage(Bg, ldsB[1], 64); stage(Ag, ldsA[1], 64);
    __builtin_amdgcn_s_waitcnt(0x0F78);   // vmcnt(8): tile0 landed
    __builtin_amdgcn_sched_barrier(0);
    __builtin_amdgcn_s_barrier();
    __builtin_amdgcn_sched_barrier(0);

    #pragma unroll 1
    for (int kt = 0; kt < NKT_; kt++) {
        const int bo = (kt & 1) ? 8192 : 0;
        bf16x8 a[8], b[8];
        // straight-line body: compiler interleaves reads & MFMAs with
        // counted lgkm waits; cross-BLOCK overlap does the pipe hiding.
        #pragma unroll
        for (int mf = 0; mf < 4; mf++) {
            a[mf*2+0] = ldb8(aB0 + bo + mf*1024);
            a[mf*2+1] = ldb8(aB1 + bo + mf*1024);
        }
        #pragma unroll
        for (int nf = 0; nf < 4; nf++) {
            b[nf*2+0] = ldb8(bB0 + bo + nf*1024);
            b[nf*2+1] = ldb8(bB1 + bo + nf*1024);
        }
        __builtin_amdgcn_s_setprio(1);
        #pragma unroll
        for (int mf = 0; mf < 4; mf++)
            #pragma unroll
            for (int nf = 0; nf < 4; nf++) {
                MFMA16(a[mf*2+0], b[nf*2+0], acc[mf][nf]);
                MFMA16(a[mf*2+1], b[nf*2+1], acc[mf][nf]);
            }
        __builtin_amdgcn_s_setprio(0);
        if (kt < NKT_ - 1) {
            __builtin_amdgcn_sched_barrier(0);
            __builtin_amdgcn_s_barrier();      // Bar1: cur buf read-complete
            __builtin_amdgcn_sched_barrier(0);
            if (kt < NKT_ - 2) {
                stage(Bg, ldsB[kt & 1], (kt + 2) << 6);
                stage(Ag, ldsA[kt & 1], (kt + 2) << 6);
                __builtin_amdgcn_s_waitcnt(0x0F78);  // vmcnt(8): kt+1 landed
            } else {
                __builtin_amdgcn_s_waitcnt(0x0F70);  // vmcnt(0): drain tail
            }
            __builtin_amdgcn_sched_barrier(0);
            __builtin_amdgcn_s_barrier();      // Bar2: nxt buf certified
            __builtin_amdgcn_sched_barrier(0);
        }
    }
    __syncthreads();   // quiesce before epilogue LDS reuse

    // ---------------- epilogues ----------------
    if constexpr (EPI == 0) {
        if (bn >= 2048) {
            // v tile: plain bf16 to vbuf [row][512] (original d-order)
            const int cb = bn - 2048 + WN * 64;
            #pragma unroll
            for (int mf = 0; mf < 4; mf++) {
                const int rl = WM*64 + mf*16 + quad*4;
                #pragma unroll
                for (int reg = 0; reg < 4; reg++) {
                    ushort* vr = vbuf + (size_t)(bm + rl + reg) * 512 + cb + m16;
                    #pragma unroll
                    for (int nf = 0; nf < 4; nf++)
                        vr[nf*16] = f2bf(acc[mf][nf][reg]);
                }
            }
        } else {
            // q/k tile (one head per tile): RMS (rotation-invariant) + rope
            float* ssqS = (float*)&ldsA[0][0];   // [128][2] floats, 1 KB
            #pragma unroll
            for (int mf = 0; mf < 4; mf++) {
                #pragma unroll
                for (int reg = 0; reg < 4; reg++) {
                    float v = acc[mf][0][reg]*acc[mf][0][reg] + acc[mf][1][reg]*acc[mf][1][reg]
                            + acc[mf][2][reg]*acc[mf][2][reg] + acc[mf][3][reg]*acc[mf][3][reg];
                    v += __shfl_xor(v, 1); v += __shfl_xor(v, 2);
                    v += __shfl_xor(v, 4); v += __shfl_xor(v, 8);
                    if (m16 == 0) {
                        const int rl = WM*64 + mf*16 + quad*4 + reg;
                        ssqS[rl*2 + WN] = v;   // wave's 64-col partial
                    }
                }
            }
            __syncthreads();

            const bool isq = (bn < 1536);
            const float osc = isq ? (1.2f * 1.2f * 0.08838834764831845f) : 1.0f;
            const int hh  = isq ? (bn >> 7) : ((bn - 1536) >> 7);
            const int nh  = isq ? H_ : KV_;
            ushort* outp  = isq ? Qp : Kp;

            #pragma unroll
            for (int mf = 0; mf < 4; mf++) {
                #pragma unroll
                for (int reg = 0; reg < 4; reg++) {
                    const int rl = WM*64 + mf*16 + quad*4 + reg;
                    const int row = bm + rl;
                    const float tot = ssqS[rl*2] + ssqS[rl*2 + 1];
                    const float sc = rsqrtf(tot * (1.0f/128.0f) + 1.1920928955078125e-07f) * osc;
                    const int b = row >> 11, t = row & (T_ - 1);
                    ushort* orow = outp + ((size_t)(b * nh + hh) * T_ + t) * D_;
                    #pragma unroll
                    for (int nf = 0; nf < 2; nf++) {
                        // wave's 64-col half contains complete rope pairs 32 apart
                        const int ipair = WN * 32 + nf*16 + m16;
                        const float c = cosb[t*64 + ipair], s = sinb[t*64 + ipair];
                        const float x1 = acc[mf][nf][reg], x2 = acc[mf][nf+2][reg];
                        const int oc = WN * 64 + nf*16 + m16;
                        orow[oc]      = f2bf((x1*c + x2*s) * sc);
                        orow[oc + 32] = f2bf((x2*c - x1*s) * sc);
                    }
                }
            }
        }
    } else {
        // plain fp32 C
        #pragma unroll
        for (int mf = 0; mf < 4; mf++) {
            const int rl = WM*64 + mf*16 + quad*4;
            #pragma unroll
            for (int reg = 0; reg < 4; reg++) {
                float* cr = Cf + (size_t)(bm + rl + reg) * C_ + bn + WN*64 + m16;
                #pragma unroll
                for (int nf = 0; nf < 4; nf++)
                    cr[nf*16] = acc[mf][nf][reg];
            }
        }
    }
}

// ---------------------------------------------------------------------------
// Fused segmented fp32->bf16 cast of x, Wq, Wk, Wv, Wproj (one launch).
// ---------------------------------------------------------------------------
#define SEG0 1572864   // x      : 4096*1536/4
#define SEG1 2162688   // + Wq   : 1536*1536/4
#define SEG2 2359296   // + Wk   : 512*1536/4
#define SEG3 2555904   // + Wv   : 512*1536/4
#define SEG4 3145728   // + Wproj: 1536*1536/4
#define ROW4 384       // float4s per 1536-col row
__global__ __launch_bounds__(256) void cast_all(const float* __restrict__ x,
                                                const float* __restrict__ Wq,
                                                const float* __restrict__ Wk,
                                                const float* __restrict__ Wv,
                                                const float* __restrict__ Wp,
                                                ushort* __restrict__ xb,
                                                ushort* __restrict__ Wqkvb,
                                                ushort* __restrict__ Wpb) {
    const int i = blockIdx.x * 256 + threadIdx.x;
    float4 v; size_t dst4; ushort* dstp;
    if (i < SEG0) {
        v = ((const float4*)x)[i]; dstp = xb; dst4 = i;
    } else if (i < SEG1) {
        const int j = i - SEG0;
        const int r = j / ROW4, c4 = j - r * ROW4;
        const int d = r & 127, hh = r >> 7;
        v = ((const float4*)Wq)[j]; dstp = Wqkvb;
        dst4 = (size_t)(hh * 128 + dperm(d)) * ROW4 + c4;
    } else if (i < SEG2) {
        const int j = i - SEG1;
        const int r = j / ROW4, c4 = j - r * ROW4;
        const int d = r & 127, g = r >> 7;
        v = ((const float4*)Wk)[j]; dstp = Wqkvb;
        dst4 = (size_t)(1536 + g * 128 + dperm(d)) * ROW4 + c4;
    } else if (i < SEG3) {
        const int j = i - SEG2;
        v = ((const float4*)Wv)[j]; dstp = Wqkvb;
        dst4 = (size_t)2048 * ROW4 + j;
    } else {
        const int j = i - SEG3;
        v = ((const float4*)Wp)[j]; dstp = Wpb; dst4 = j;
    }
    ((ushort4*)dstp)[dst4] = make_ushort4(f2bf(v.x), f2bf(v.y), f2bf(v.z), f2bf(v.w));
}

// ---------------------------------------------------------------------------
// Fused ve-gate + transpose: Vt[b][g][d][s] = vbuf[bt][g*128+d] + gate*ve
// ---------------------------------------------------------------------------
__global__ __launch_bounds__(256) void gate_vt(const ushort* __restrict__ vbuf,
                                               const float* __restrict__ x,
                                               const float* __restrict__ ve,
                                               const float* __restrict__ Wg,
                                               ushort* __restrict__ Vt) {
    const int t0 = blockIdx.x * 64, g = blockIdx.y, b = blockIdx.z;
    __shared__ float gateS[64];
    __shared__ ushort tile[128][66];   // [d][t], padded
    const int tid = threadIdx.x;
    if (tid < 64) {
        const float* xr = x + (size_t)(b * T_ + t0 + tid) * C_;
        float acc = 0.f;
        #pragma unroll
        for (int c = 0; c < 12; c++) acc += xr[c] * Wg[g * 12 + c];
        gateS[tid] = 3.0f / (1.0f + __expf(-acc));
    }
    __syncthreads();
    #pragma unroll
    for (int i = 0; i < 32; i++) {
        int idx = i * 256 + tid;       // 0..8191
        int r = idx >> 7;              // t within tile
        int d = idx & 127;
        size_t offv = (size_t)(b * T_ + t0 + r) * 512 + g * D_ + d;
        tile[d][r] = f2bf(bf2f(vbuf[offv]) + gateS[r] * ve[offv]);
    }
    __syncthreads();
    ushort* ob = Vt + ((size_t)(b * KV_ + g) * D_) * T_ + t0;
    #pragma unroll
    for (int i = 0; i < 32; i++) {
        int idx = i * 256 + tid;
        int d = idx >> 6;              // 0..127
        int c = idx & 63;
        ob[(size_t)d * T_ + c] = tile[d][c];
    }
}

// ---------------------------------------------------------------------------
// Flash attention: block = (b, h, 64 queries), 4 waves x 16 queries.
// ---------------------------------------------------------------------------
__global__ __launch_bounds__(256, 3) void attn_mfma(const ushort* __restrict__ Qp,
                                                    const ushort* __restrict__ Kp,
                                                    const ushort* __restrict__ Vt,
                                                    ushort* __restrict__ Y,
                                                    const int* __restrict__ wptr) {
    const int t0 = blockIdx.x * 64;
    const int h  = blockIdx.y, b = blockIdx.z;
    const int g  = h / REP_;
    const int tid  = threadIdx.x;
    const int wave = tid >> 6, lane = tid & 63;
    const int m16 = lane & 15, quad = lane >> 4;

    __shared__ ushort Ks[4 * 32 * 32];   // 8 KB
    __shared__ ushort Vs[128 * 32];      // 8 KB
    __shared__ ushort Pl[4][16 * 40];    // 5 KB, per-wave P buffers

    const int w = *wptr;
    const bool windowed = (w >= 0 && w < T_);
    const unsigned wu = windowed ? (unsigned)w : 0x7FFFFFFFu;
    int s_lo = 0;
    if (windowed) { s_lo = t0 - w; if (s_lo < 0) s_lo = 0; }
    const int s_hi = t0 + 63;
    const int ss0 = s_lo & ~31;
    const int tw = t0 + wave * 16;

    const ushort* qrow = Qp + ((size_t)(b * H_ + h) * T_ + tw + m16) * D_ + quad * 8;
    bf16x8 qa[4];
    #pragma unroll
    for (int kc = 0; kc < 4; kc++) qa[kc] = ldb8(qrow + kc * 32);

    const ushort* kbase = Kp + (size_t)(b * KV_ + g) * T_ * D_;
    const ushort* vbase = Vt + (size_t)(b * KV_ + g) * D_ * T_;

    const int c0 = wave, c1 = wave + 4;
    const ushort* kg0 = kbase + (size_t)((c0 & 1) * 16 + (lane >> 2)) * D_ + (c0 >> 1) * 32 + (lane & 3) * 8;
    const ushort* kg1 = kbase + (size_t)((c1 & 1) * 16 + (lane >> 2)) * D_ + (c1 >> 1) * 32 + (lane & 3) * 8;
    ushort* kl0 = Ks + c0 * 512;
    ushort* kl1 = Ks + c1 * 512;
    const ushort* vg0 = vbase + (size_t)(c0 * 16 + (lane >> 2)) * T_ + (lane & 3) * 8;
    const ushort* vg1 = vbase + (size_t)(c1 * 16 + (lane >> 2)) * T_ + (lane & 3) * 8;
    ushort* vl0 = Vs + c0 * 512;
    ushort* vl1 = Vs + c1 * 512;

    f32x4 o[8];
    #pragma unroll
    for (int dt = 0; dt < 8; dt++) o[dt] = (f32x4){0.f, 0.f, 0.f, 0.f};
    f32x4 lacc = (f32x4){0.f, 0.f, 0.f, 0.f};
    BCast onesc; onesc.u = (u32x4){0x3F803F80u, 0x3F803F80u, 0x3F803F80u, 0x3F803F80u};
    const bf16x8 ones = onesc.b;
    ushort* pw = &Pl[wave][0];

    for (int ss = ss0; ss <= s_hi; ss += 32) {
        const size_t koff = (size_t)ss * D_;
        async_copy16(kg0 + koff, kl0);
        async_copy16(kg1 + koff, kl1);
        async_copy16(vg0 + ss,   vl0);
        async_copy16(vg1 + ss,   vl1);
        __syncthreads();

        f32x4 s0 = (f32x4){0.f,0.f,0.f,0.f};
        f32x4 s1 = (f32x4){0.f,0.f,0.f,0.f};
        #pragma unroll
        for (int kc = 0; kc < 4; kc++) {
            bf16x8 kf0 = ldb8(Ks + kc * 1024 + m16 * 32 + quad * 8);
            bf16x8 kf1 = ldb8(Ks + kc * 1024 + (16 + m16) * 32 + quad * 8);
            s0 = __builtin_amdgcn_mfma_f32_16x16x32_bf16(qa[kc], kf0, s0, 0, 0, 0);
            s1 = __builtin_amdgcn_mfma_f32_16x16x32_bf16(qa[kc], kf1, s1, 0, 0, 0);
        }

        const int sA = ss + m16, sB = ss + 16 + m16;
        #pragma unroll
        for (int reg = 0; reg < 4; reg++) {
            const int t = tw + quad * 4 + reg;
            const float pa = ((unsigned)(t - sA) <= wu) ? __expf(s0[reg]) : 0.f;
            const float pb = ((unsigned)(t - sB) <= wu) ? __expf(s1[reg]) : 0.f;
            pw[(quad * 4 + reg) * 40 + m16]      = f2bf(pa);
            pw[(quad * 4 + reg) * 40 + 16 + m16] = f2bf(pb);
        }

        __builtin_amdgcn_s_waitcnt(0xc07f);   // lgkmcnt(0), leave vmcnt alone
        bf16x8 pfrag = ldb8(pw + m16 * 40 + quad * 8);

        #pragma unroll
        for (int dt = 0; dt < 8; dt++) {
            bf16x8 vf = ldb8(Vs + (dt * 16 + m16) * 32 + quad * 8);
            o[dt] = __builtin_amdgcn_mfma_f32_16x16x32_bf16(pfrag, vf, o[dt], 0, 0, 0);
        }
        lacc = __builtin_amdgcn_mfma_f32_16x16x32_bf16(pfrag, ones, lacc, 0, 0, 0);
        __syncthreads();
    }

    float inv[4];
    #pragma unroll
    for (int reg = 0; reg < 4; reg++) inv[reg] = 1.0f / lacc[reg];
    ushort* yb = Y + ((size_t)(b * T_ + tw + quad * 4) * H_ + h) * D_ + m16;
    #pragma unroll
    for (int reg = 0; reg < 4; reg++)
        #pragma unroll
        for (int dt = 0; dt < 8; dt++)
            yb[(size_t)reg * H_ * D_ + dt * 16] = f2bf(o[dt][reg] * inv[reg]);
}

// ---------------------------------------------------------------------------
extern "C" void kernel_launch(void* const* d_in, const int* in_sizes, int n_in,
                              void* d_out, int out_size, void* d_ws, size_t ws_size,
                              hipStream_t stream) {
    const float* x     = (const float*)d_in[0];
    const float* ve    = (const float*)d_in[1];
    const float* cosb  = (const float*)d_in[2];
    const float* sinb  = (const float*)d_in[3];
    const float* Wq    = (const float*)d_in[4];
    const float* Wk    = (const float*)d_in[5];
    const float* Wv    = (const float*)d_in[6];
    const float* Wproj = (const float*)d_in[7];
    const float* Wg    = (const float*)d_in[8];
    const int*   wptr  = (const int*)d_in[9];
    float* out = (float*)d_out;

    // workspace layout (all bf16/ushort), ~63 MB
    ushort* xb    = (ushort*)d_ws;                    // M*C
    ushort* vbuf  = xb    + (size_t)M_ * C_;          // M*512
    ushort* Qp    = vbuf  + (size_t)M_ * 512;         // M*C (permuted d)
    ushort* Kp    = Qp    + (size_t)M_ * C_;          // M*512 (permuted d)
    ushort* Vt    = Kp    + (size_t)M_ * 512;         // M*512
    ushort* yb16  = Vt    + (size_t)M_ * 512;         // M*C
    ushort* Wqkvb = yb16  + (size_t)M_ * C_;          // 2560*C (q/k rows dperm'd)
    ushort* Wpb   = Wqkvb + (size_t)NQKV_ * C_;       // C*C

    cast_all<<<SEG4 / 256, 256, 0, stream>>>(x, Wq, Wk, Wv, Wproj, xb, Wqkvb, Wpb);

    gemm128<0><<<dim3(NQKV_ / 128, M_ / 128), 256, 0, stream>>>(
        xb, Wqkvb, Qp, Kp, vbuf, nullptr, cosb, sinb);

    gate_vt<<<dim3(T_ / 64, KV_, B_), 256, 0, stream>>>(vbuf, x, ve, Wg, Vt);

    attn_mfma<<<dim3(T_ / 64, H_, B_), 256, 0, stream>>>(Qp, Kp, Vt, yb16, wptr);

    gemm128<1><<<dim3(C_ / 128, M_ / 128), 256, 0, stream>>>(
        yb16, Wpb, nullptr, nullptr, nullptr, out, nullptr, nullptr);
}

// Round 7
// 255.090 us; speedup vs baseline: 3.1603x; 1.0136x over previous
//
#include <hip/hip_runtime.h>
#include <hip/hip_bf16.h>
#include <math.h>

// Problem constants
#define B_  2
#define T_  2048
#define C_  1536
#define H_  12
#define KV_ 4
#define D_  128
#define M_  (B_*T_)   // 4096 rows
#define REP_ (H_/KV_) // 3
#define NQKV_ 2560    // fused q|k|v output width
#define KK_  1536     // K for both big GEMMs
#define NKT_ 24       // KK_/64 K-tiles

typedef __bf16 bf16x8 __attribute__((ext_vector_type(8)));
typedef float  f32x4  __attribute__((ext_vector_type(4)));
typedef unsigned u32x4 __attribute__((ext_vector_type(4)));

union BCast { u32x4 u; bf16x8 b; };

__device__ inline bf16x8 ldb8(const ushort* p) {
    BCast c; c.u = *reinterpret_cast<const u32x4*>(p); return c.b;
}

__device__ inline ushort f2bf(float f) {
    union { float f; unsigned u; } v; v.f = f;
    unsigned u = v.u;
    return (ushort)((u + 0x7FFF + ((u >> 16) & 1)) >> 16);
}

__device__ inline float bf2f(ushort u) {
    union { unsigned u; float f; } v; v.u = (unsigned)u << 16;
    return v.f;
}

// async global->LDS, 16 bytes per lane; lds base must be wave-uniform
__device__ inline void async_copy16(const ushort* g, ushort* l) {
    __builtin_amdgcn_global_load_lds(
        (const __attribute__((address_space(1))) unsigned*)g,
        (__attribute__((address_space(3))) unsigned*)l, 16, 0, 0);
}

// d-permutation for rope-pair locality: swap middle two 32-blocks of each head.
__device__ __host__ inline int dperm(int d) {
    return (d < 32) ? d : (d < 64 ? d + 32 : (d < 96 ? d - 32 : d));
}

#define MFMA16(va, vb, d) d = __builtin_amdgcn_mfma_f32_16x16x32_bf16(va, vb, d, 0, 0, 0)

// ---------------------------------------------------------------------------
// 128x128 GEMM, 2 blocks/CU: C[M,N] = A[M,K]*B[N,K]^T.  (unchanged from r6 —
// control for this round; structural ceiling for this shape at HIP source
// level established over r1-r6: 424-474 TF across six schedule variants.)
// ---------------------------------------------------------------------------
template<int EPI>
__global__ __launch_bounds__(256, 2) void gemm128(const ushort* __restrict__ A,
                                                  const ushort* __restrict__ Bm,
                                                  ushort* __restrict__ Qp,
                                                  ushort* __restrict__ Kp,
                                                  ushort* __restrict__ vbuf,
                                                  float* __restrict__ Cf,
                                                  const float* __restrict__ cosb,
                                                  const float* __restrict__ sinb) {
    __shared__ ushort ldsA[2][8192];   // [buf][128 rows x 64 cols]
    __shared__ ushort ldsB[2][8192];
    const int tid  = threadIdx.x;
    const int wave = tid >> 6, lane = tid & 63;
    const int m16 = lane & 15, quad = lane >> 4;
    const int WM = wave >> 1, WN = wave & 1;

    const int nwg  = gridDim.x * gridDim.y;
    const int orig = blockIdx.y * gridDim.x + blockIdx.x;
    const int vid  = (orig & 7) * (nwg >> 3) + (orig >> 3);
    const int gy   = gridDim.y;            // 32
    const int bxT  = vid / gy;
    const int byT  = vid - bxT * gy;
    const int bm = byT << 7, bn = bxT << 7;

    const int r = tid >> 3;                              // 0..31
    const int slot8 = ((tid & 7) ^ (r & 7)) << 3;        // swizzled col (elems)
    const ushort* Ag = A  + (size_t)(bm + r) * KK_ + slot8;
    const ushort* Bg = Bm + (size_t)(bn + r) * KK_ + slot8;
    const size_t row32 = (size_t)32 * KK_;

    auto stage = [&](const ushort* Gp, ushort* ldsOp, int kc) {
        ushort* base = ldsOp + wave * 512;   // wave-uniform, lanes add 16B
        const ushort* g = Gp + kc;
        async_copy16(g,             base);
        async_copy16(g +   row32,   base + 2048);
        async_copy16(g + 2*row32,   base + 4096);
        async_copy16(g + 3*row32,   base + 6144);
    };

    const int swzu = (m16 & 7) << 3;
    const int k0u  = (quad * 8) ^ swzu;
    const int k1u  = (32 + quad * 8) ^ swzu;
    const ushort* aB0 = &ldsA[0][0] + ((WM * 64 + m16) << 6) + k0u;
    const ushort* aB1 = &ldsA[0][0] + ((WM * 64 + m16) << 6) + k1u;
    const ushort* bB0 = &ldsB[0][0] + ((WN * 64 + m16) << 6) + k0u;
    const ushort* bB1 = &ldsB[0][0] + ((WN * 64 + m16) << 6) + k1u;

    f32x4 acc[4][4];
    #pragma unroll
    for (int i = 0; i < 4; i++)
        #pragma unroll
        for (int j = 0; j < 4; j++) acc[i][j] = (f32x4){0.f, 0.f, 0.f, 0.f};

    stage(Bg, ldsB[0], 0);  stage(Ag, ldsA[0], 0);
    stage(Bg, ldsB[1], 64); stage(Ag, ldsA[1], 64);
    __builtin_amdgcn_s_waitcnt(0x0F78);   // vmcnt(8): tile0 landed
    __builtin_amdgcn_sched_barrier(0);
    __builtin_amdgcn_s_barrier();
    __builtin_amdgcn_sched_barrier(0);

    #pragma unroll 1
    for (int kt = 0; kt < NKT_; kt++) {
        const int bo = (kt & 1) ? 8192 : 0;
        bf16x8 a[8], b[8];
        #pragma unroll
        for (int mf = 0; mf < 4; mf++) {
            a[mf*2+0] = ldb8(aB0 + bo + mf*1024);
            a[mf*2+1] = ldb8(aB1 + bo + mf*1024);
        }
        #pragma unroll
        for (int nf = 0; nf < 4; nf++) {
            b[nf*2+0] = ldb8(bB0 + bo + nf*1024);
            b[nf*2+1] = ldb8(bB1 + bo + nf*1024);
        }
        __builtin_amdgcn_s_setprio(1);
        #pragma unroll
        for (int mf = 0; mf < 4; mf++)
            #pragma unroll
            for (int nf = 0; nf < 4; nf++) {
                MFMA16(a[mf*2+0], b[nf*2+0], acc[mf][nf]);
                MFMA16(a[mf*2+1], b[nf*2+1], acc[mf][nf]);
            }
        __builtin_amdgcn_s_setprio(0);
        if (kt < NKT_ - 1) {
            __builtin_amdgcn_sched_barrier(0);
            __builtin_amdgcn_s_barrier();      // Bar1: cur buf read-complete
            __builtin_amdgcn_sched_barrier(0);
            if (kt < NKT_ - 2) {
                stage(Bg, ldsB[kt & 1], (kt + 2) << 6);
                stage(Ag, ldsA[kt & 1], (kt + 2) << 6);
                __builtin_amdgcn_s_waitcnt(0x0F78);  // vmcnt(8): kt+1 landed
            } else {
                __builtin_amdgcn_s_waitcnt(0x0F70);  // vmcnt(0): drain tail
            }
            __builtin_amdgcn_sched_barrier(0);
            __builtin_amdgcn_s_barrier();      // Bar2: nxt buf certified
            __builtin_amdgcn_sched_barrier(0);
        }
    }
    __syncthreads();   // quiesce before epilogue LDS reuse

    if constexpr (EPI == 0) {
        if (bn >= 2048) {
            const int cb = bn - 2048 + WN * 64;
            #pragma unroll
            for (int mf = 0; mf < 4; mf++) {
                const int rl = WM*64 + mf*16 + quad*4;
                #pragma unroll
                for (int reg = 0; reg < 4; reg++) {
                    ushort* vr = vbuf + (size_t)(bm + rl + reg) * 512 + cb + m16;
                    #pragma unroll
                    for (int nf = 0; nf < 4; nf++)
                        vr[nf*16] = f2bf(acc[mf][nf][reg]);
                }
            }
        } else {
            float* ssqS = (float*)&ldsA[0][0];   // [128][2] floats, 1 KB
            #pragma unroll
            for (int mf = 0; mf < 4; mf++) {
                #pragma unroll
                for (int reg = 0; reg < 4; reg++) {
                    float v = acc[mf][0][reg]*acc[mf][0][reg] + acc[mf][1][reg]*acc[mf][1][reg]
                            + acc[mf][2][reg]*acc[mf][2][reg] + acc[mf][3][reg]*acc[mf][3][reg];
                    v += __shfl_xor(v, 1); v += __shfl_xor(v, 2);
                    v += __shfl_xor(v, 4); v += __shfl_xor(v, 8);
                    if (m16 == 0) {
                        const int rl = WM*64 + mf*16 + quad*4 + reg;
                        ssqS[rl*2 + WN] = v;
                    }
                }
            }
            __syncthreads();

            const bool isq = (bn < 1536);
            const float osc = isq ? (1.2f * 1.2f * 0.08838834764831845f) : 1.0f;
            const int hh  = isq ? (bn >> 7) : ((bn - 1536) >> 7);
            const int nh  = isq ? H_ : KV_;
            ushort* outp  = isq ? Qp : Kp;

            #pragma unroll
            for (int mf = 0; mf < 4; mf++) {
                #pragma unroll
                for (int reg = 0; reg < 4; reg++) {
                    const int rl = WM*64 + mf*16 + quad*4 + reg;
                    const int row = bm + rl;
                    const float tot = ssqS[rl*2] + ssqS[rl*2 + 1];
                    const float sc = rsqrtf(tot * (1.0f/128.0f) + 1.1920928955078125e-07f) * osc;
                    const int b = row >> 11, t = row & (T_ - 1);
                    ushort* orow = outp + ((size_t)(b * nh + hh) * T_ + t) * D_;
                    #pragma unroll
                    for (int nf = 0; nf < 2; nf++) {
                        const int ipair = WN * 32 + nf*16 + m16;
                        const float c = cosb[t*64 + ipair], s = sinb[t*64 + ipair];
                        const float x1 = acc[mf][nf][reg], x2 = acc[mf][nf+2][reg];
                        const int oc = WN * 64 + nf*16 + m16;
                        orow[oc]      = f2bf((x1*c + x2*s) * sc);
                        orow[oc + 32] = f2bf((x2*c - x1*s) * sc);
                    }
                }
            }
        }
    } else {
        #pragma unroll
        for (int mf = 0; mf < 4; mf++) {
            const int rl = WM*64 + mf*16 + quad*4;
            #pragma unroll
            for (int reg = 0; reg < 4; reg++) {
                float* cr = Cf + (size_t)(bm + rl + reg) * C_ + bn + WN*64 + m16;
                #pragma unroll
                for (int nf = 0; nf < 4; nf++)
                    cr[nf*16] = acc[mf][nf][reg];
            }
        }
    }
}

// ---------------------------------------------------------------------------
// Fused segmented fp32->bf16 cast of x, Wq, Wk, Wv, Wproj (one launch).
// ---------------------------------------------------------------------------
#define SEG0 1572864   // x      : 4096*1536/4
#define SEG1 2162688   // + Wq   : 1536*1536/4
#define SEG2 2359296   // + Wk   : 512*1536/4
#define SEG3 2555904   // + Wv   : 512*1536/4
#define SEG4 3145728   // + Wproj: 1536*1536/4
#define ROW4 384       // float4s per 1536-col row
__global__ __launch_bounds__(256) void cast_all(const float* __restrict__ x,
                                                const float* __restrict__ Wq,
                                                const float* __restrict__ Wk,
                                                const float* __restrict__ Wv,
                                                const float* __restrict__ Wp,
                                                ushort* __restrict__ xb,
                                                ushort* __restrict__ Wqkvb,
                                                ushort* __restrict__ Wpb) {
    const int i = blockIdx.x * 256 + threadIdx.x;
    float4 v; size_t dst4; ushort* dstp;
    if (i < SEG0) {
        v = ((const float4*)x)[i]; dstp = xb; dst4 = i;
    } else if (i < SEG1) {
        const int j = i - SEG0;
        const int r = j / ROW4, c4 = j - r * ROW4;
        const int d = r & 127, hh = r >> 7;
        v = ((const float4*)Wq)[j]; dstp = Wqkvb;
        dst4 = (size_t)(hh * 128 + dperm(d)) * ROW4 + c4;
    } else if (i < SEG2) {
        const int j = i - SEG1;
        const int r = j / ROW4, c4 = j - r * ROW4;
        const int d = r & 127, g = r >> 7;
        v = ((const float4*)Wk)[j]; dstp = Wqkvb;
        dst4 = (size_t)(1536 + g * 128 + dperm(d)) * ROW4 + c4;
    } else if (i < SEG3) {
        const int j = i - SEG2;
        v = ((const float4*)Wv)[j]; dstp = Wqkvb;
        dst4 = (size_t)2048 * ROW4 + j;
    } else {
        const int j = i - SEG3;
        v = ((const float4*)Wp)[j]; dstp = Wpb; dst4 = j;
    }
    ((ushort4*)dstp)[dst4] = make_ushort4(f2bf(v.x), f2bf(v.y), f2bf(v.z), f2bf(v.w));
}

// ---------------------------------------------------------------------------
// Fused ve-gate + transpose: Vt[b][g][d][s] = vbuf[bt][g*128+d] + gate*ve
// ---------------------------------------------------------------------------
__global__ __launch_bounds__(256) void gate_vt(const ushort* __restrict__ vbuf,
                                               const float* __restrict__ x,
                                               const float* __restrict__ ve,
                                               const float* __restrict__ Wg,
                                               ushort* __restrict__ Vt) {
    const int t0 = blockIdx.x * 64, g = blockIdx.y, b = blockIdx.z;
    __shared__ float gateS[64];
    __shared__ ushort tile[128][66];   // [d][t], padded
    const int tid = threadIdx.x;
    if (tid < 64) {
        const float* xr = x + (size_t)(b * T_ + t0 + tid) * C_;
        float acc = 0.f;
        #pragma unroll
        for (int c = 0; c < 12; c++) acc += xr[c] * Wg[g * 12 + c];
        gateS[tid] = 3.0f / (1.0f + __expf(-acc));
    }
    __syncthreads();
    #pragma unroll
    for (int i = 0; i < 32; i++) {
        int idx = i * 256 + tid;       // 0..8191
        int r = idx >> 7;              // t within tile
        int d = idx & 127;
        size_t offv = (size_t)(b * T_ + t0 + r) * 512 + g * D_ + d;
        tile[d][r] = f2bf(bf2f(vbuf[offv]) + gateS[r] * ve[offv]);
    }
    __syncthreads();
    ushort* ob = Vt + ((size_t)(b * KV_ + g) * D_) * T_ + t0;
    #pragma unroll
    for (int i = 0; i < 32; i++) {
        int idx = i * 256 + tid;
        int d = idx >> 6;              // 0..127
        int c = idx & 63;
        ob[(size_t)d * T_ + c] = tile[d][c];
    }
}

// ---------------------------------------------------------------------------
// Flash attention: block = (b, h, 64 queries), 4 waves x 16 queries.
// r7 CHANGE (T3/T14 port of the r6 GEMM handoff): K/V double-buffered,
// compute[st] overlaps stage[st+2]; the two FULL-DRAIN __syncthreads per
// 32-key step are replaced by {Bar1 -> stage -> vmcnt(4) -> Bar2} with
// counted vmcnt (never 0 mid-loop). P round-trip keeps private lgkm waits.
// NST >= 2 always (s_hi - ss0 >= 63). LDS 37 KB.
// ---------------------------------------------------------------------------
__global__ __launch_bounds__(256, 3) void attn_mfma(const ushort* __restrict__ Qp,
                                                    const ushort* __restrict__ Kp,
                                                    const ushort* __restrict__ Vt,
                                                    ushort* __restrict__ Y,
                                                    const int* __restrict__ wptr) {
    const int t0 = blockIdx.x * 64;
    const int h  = blockIdx.y, b = blockIdx.z;
    const int g  = h / REP_;
    const int tid  = threadIdx.x;
    const int wave = tid >> 6, lane = tid & 63;
    const int m16 = lane & 15, quad = lane >> 4;

    __shared__ ushort Ks[2][4096];       // [buf][4 kc x 2 halves x 16 x 32]
    __shared__ ushort Vs[2][4096];       // [buf][128 d x 32 keys]
    __shared__ ushort Pl[4][16 * 40];    // per-wave P buffers

    const int w = *wptr;
    const bool windowed = (w >= 0 && w < T_);
    const unsigned wu = windowed ? (unsigned)w : 0x7FFFFFFFu;
    int s_lo = 0;
    if (windowed) { s_lo = t0 - w; if (s_lo < 0) s_lo = 0; }
    const int s_hi = t0 + 63;
    const int ss0 = s_lo & ~31;
    const int NST = ((s_hi - ss0) >> 5) + 1;   // >= 2 always
    const int tw = t0 + wave * 16;

    const ushort* qrow = Qp + ((size_t)(b * H_ + h) * T_ + tw + m16) * D_ + quad * 8;
    bf16x8 qa[4];
    #pragma unroll
    for (int kc = 0; kc < 4; kc++) qa[kc] = ldb8(qrow + kc * 32);

    const ushort* kbase = Kp + (size_t)(b * KV_ + g) * T_ * D_;
    const ushort* vbase = Vt + (size_t)(b * KV_ + g) * D_ * T_;

    const int c0 = wave, c1 = wave + 4;
    const ushort* kg0 = kbase + (size_t)((c0 & 1) * 16 + (lane >> 2)) * D_ + (c0 >> 1) * 32 + (lane & 3) * 8;
    const ushort* kg1 = kbase + (size_t)((c1 & 1) * 16 + (lane >> 2)) * D_ + (c1 >> 1) * 32 + (lane & 3) * 8;
    const ushort* vg0 = vbase + (size_t)(c0 * 16 + (lane >> 2)) * T_ + (lane & 3) * 8;
    const ushort* vg1 = vbase + (size_t)(c1 * 16 + (lane >> 2)) * T_ + (lane & 3) * 8;
    const int kl0o = c0 * 512, kl1o = c1 * 512;

    auto stg = [&](int st, int buf) {
        const int ss = ss0 + (st << 5);
        const size_t koff = (size_t)ss * D_;
        async_copy16(kg0 + koff, Ks[buf] + kl0o);
        async_copy16(kg1 + koff, Ks[buf] + kl1o);
        async_copy16(vg0 + ss,   Vs[buf] + kl0o);
        async_copy16(vg1 + ss,   Vs[buf] + kl1o);
    };

    f32x4 o[8];
    #pragma unroll
    for (int dt = 0; dt < 8; dt++) o[dt] = (f32x4){0.f, 0.f, 0.f, 0.f};
    f32x4 lacc = (f32x4){0.f, 0.f, 0.f, 0.f};
    BCast onesc; onesc.u = (u32x4){0x3F803F80u, 0x3F803F80u, 0x3F803F80u, 0x3F803F80u};
    const bf16x8 ones = onesc.b;
    ushort* pw = &Pl[wave][0];

    // prologue: stage steps 0,1; certify step0 (leave step1's 4 in flight)
    stg(0, 0); stg(1, 1);
    __builtin_amdgcn_s_waitcnt(0x0F74);   // vmcnt(4)
    __builtin_amdgcn_sched_barrier(0);
    __builtin_amdgcn_s_barrier();
    __builtin_amdgcn_sched_barrier(0);

    #pragma unroll 1
    for (int st = 0; st < NST; st++) {
        const int ss = ss0 + (st << 5);
        const ushort* KsB = Ks[st & 1];
        const ushort* VsB = Vs[st & 1];

        f32x4 s0 = (f32x4){0.f,0.f,0.f,0.f};
        f32x4 s1 = (f32x4){0.f,0.f,0.f,0.f};
        #pragma unroll
        for (int kc = 0; kc < 4; kc++) {
            bf16x8 kf0 = ldb8(KsB + kc * 1024 + m16 * 32 + quad * 8);
            bf16x8 kf1 = ldb8(KsB + kc * 1024 + (16 + m16) * 32 + quad * 8);
            s0 = __builtin_amdgcn_mfma_f32_16x16x32_bf16(qa[kc], kf0, s0, 0, 0, 0);
            s1 = __builtin_amdgcn_mfma_f32_16x16x32_bf16(qa[kc], kf1, s1, 0, 0, 0);
        }

        const int sA = ss + m16, sB = ss + 16 + m16;
        #pragma unroll
        for (int reg = 0; reg < 4; reg++) {
            const int t = tw + quad * 4 + reg;
            const float pa = ((unsigned)(t - sA) <= wu) ? __expf(s0[reg]) : 0.f;
            const float pb = ((unsigned)(t - sB) <= wu) ? __expf(s1[reg]) : 0.f;
            pw[(quad * 4 + reg) * 40 + m16]      = f2bf(pa);
            pw[(quad * 4 + reg) * 40 + 16 + m16] = f2bf(pb);
        }

        __builtin_amdgcn_s_waitcnt(0xc07f);   // lgkmcnt(0), leave vmcnt alone
        bf16x8 pfrag = ldb8(pw + m16 * 40 + quad * 8);

        #pragma unroll
        for (int dt = 0; dt < 8; dt++) {
            bf16x8 vf = ldb8(VsB + (dt * 16 + m16) * 32 + quad * 8);
            o[dt] = __builtin_amdgcn_mfma_f32_16x16x32_bf16(pfrag, vf, o[dt], 0, 0, 0);
        }
        lacc = __builtin_amdgcn_mfma_f32_16x16x32_bf16(pfrag, ones, lacc, 0, 0, 0);

        if (st < NST - 1) {
            __builtin_amdgcn_sched_barrier(0);
            __builtin_amdgcn_s_barrier();      // Bar1: cur buf read-complete
            __builtin_amdgcn_sched_barrier(0);
            if (st < NST - 2) {
                stg(st + 2, st & 1);
                __builtin_amdgcn_s_waitcnt(0x0F74);  // vmcnt(4): st+1 landed
            } else {
                __builtin_amdgcn_s_waitcnt(0x0F70);  // vmcnt(0): drain tail
            }
            __builtin_amdgcn_sched_barrier(0);
            __builtin_amdgcn_s_barrier();      // Bar2: nxt buf certified
            __builtin_amdgcn_sched_barrier(0);
        }
    }

    float inv[4];
    #pragma unroll
    for (int reg = 0; reg < 4; reg++) inv[reg] = 1.0f / lacc[reg];
    ushort* yb = Y + ((size_t)(b * T_ + tw + quad * 4) * H_ + h) * D_ + m16;
    #pragma unroll
    for (int reg = 0; reg < 4; reg++)
        #pragma unroll
        for (int dt = 0; dt < 8; dt++)
            yb[(size_t)reg * H_ * D_ + dt * 16] = f2bf(o[dt][reg] * inv[reg]);
}

// ---------------------------------------------------------------------------
extern "C" void kernel_launch(void* const* d_in, const int* in_sizes, int n_in,
                              void* d_out, int out_size, void* d_ws, size_t ws_size,
                              hipStream_t stream) {
    const float* x     = (const float*)d_in[0];
    const float* ve    = (const float*)d_in[1];
    const float* cosb  = (const float*)d_in[2];
    const float* sinb  = (const float*)d_in[3];
    const float* Wq    = (const float*)d_in[4];
    const float* Wk    = (const float*)d_in[5];
    const float* Wv    = (const float*)d_in[6];
    const float* Wproj = (const float*)d_in[7];
    const float* Wg    = (const float*)d_in[8];
    const int*   wptr  = (const int*)d_in[9];
    float* out = (float*)d_out;

    // workspace layout (all bf16/ushort), ~63 MB
    ushort* xb    = (ushort*)d_ws;                    // M*C
    ushort* vbuf  = xb    + (size_t)M_ * C_;          // M*512
    ushort* Qp    = vbuf  + (size_t)M_ * 512;         // M*C (permuted d)
    ushort* Kp    = Qp    + (size_t)M_ * C_;          // M*512 (permuted d)
    ushort* Vt    = Kp    + (size_t)M_ * 512;         // M*512
    ushort* yb16  = Vt    + (size_t)M_ * 512;         // M*C
    ushort* Wqkvb = yb16  + (size_t)M_ * C_;          // 2560*C (q/k rows dperm'd)
    ushort* Wpb   = Wqkvb + (size_t)NQKV_ * C_;       // C*C

    cast_all<<<SEG4 / 256, 256, 0, stream>>>(x, Wq, Wk, Wv, Wproj, xb, Wqkvb, Wpb);

    gemm128<0><<<dim3(NQKV_ / 128, M_ / 128), 256, 0, stream>>>(
        xb, Wqkvb, Qp, Kp, vbuf, nullptr, cosb, sinb);

    gate_vt<<<dim3(T_ / 64, KV_, B_), 256, 0, stream>>>(vbuf, x, ve, Wg, Vt);

    attn_mfma<<<dim3(T_ / 64, H_, B_), 256, 0, stream>>>(Qp, Kp, Vt, yb16, wptr);

    gemm128<1><<<dim3(C_ / 128, M_ / 128), 256, 0, stream>>>(
        yb16, Wpb, nullptr, nullptr, nullptr, out, nullptr, nullptr);
}